// Round 1
// baseline (2120.565 us; speedup 1.0000x reference)
//
#include <hip/hip_runtime.h>
#include <cstdint>
#include <cstddef>

#define B_   8
#define C_   512
#define N_   1024   // H*W
#define NH_  8
#define HD_  64
#define G_   32
#define CPG_ 16     // C_/G_

// ---------------------------------------------------------------------------
// Kernel 1: GroupNorm  (one block per (b, group)); writes xn in (B, C, N)
// ---------------------------------------------------------------------------
__global__ __launch_bounds__(256) void gn_kernel(const float* __restrict__ x,
                                                 const float* __restrict__ gw,
                                                 const float* __restrict__ gb,
                                                 float* __restrict__ xn) {
  int bid = blockIdx.x;
  int b = bid >> 5, g = bid & 31;
  const float* base = x + ((size_t)b * C_ + (size_t)g * CPG_) * N_;
  float4 vals[16];
  float4 s4 = {0.f, 0.f, 0.f, 0.f}, q4 = {0.f, 0.f, 0.f, 0.f};
#pragma unroll
  for (int u = 0; u < 16; ++u) {
    float4 v = *(const float4*)(base + (size_t)u * N_ + threadIdx.x * 4);
    vals[u] = v;
    s4.x += v.x; s4.y += v.y; s4.z += v.z; s4.w += v.w;
    q4.x += v.x * v.x; q4.y += v.y * v.y; q4.z += v.z * v.z; q4.w += v.w * v.w;
  }
  float s = (s4.x + s4.y) + (s4.z + s4.w);
  float q = (q4.x + q4.y) + (q4.z + q4.w);
#pragma unroll
  for (int off = 32; off; off >>= 1) {
    s += __shfl_xor(s, off);
    q += __shfl_xor(q, off);
  }
  __shared__ float sm[4], sq[4];
  __shared__ float smean, srstd;
  int wid = threadIdx.x >> 6;
  if ((threadIdx.x & 63) == 0) { sm[wid] = s; sq[wid] = q; }
  __syncthreads();
  if (threadIdx.x == 0) {
    float S = (sm[0] + sm[1]) + (sm[2] + sm[3]);
    float Q = (sq[0] + sq[1]) + (sq[2] + sq[3]);
    float mean = S * (1.0f / 16384.0f);
    float var  = Q * (1.0f / 16384.0f) - mean * mean;
    smean = mean;
    srstd = rsqrtf(var + 1e-5f);
  }
  __syncthreads();
  float mean = smean, rstd = srstd;
  float* dst = xn + ((size_t)b * C_ + (size_t)g * CPG_) * N_;
#pragma unroll
  for (int u = 0; u < 16; ++u) {
    int c = g * CPG_ + u;
    float a  = rstd * gw[c];
    float bb = gb[c] - mean * a;
    float4 v = vals[u];
    float4 o;
    o.x = v.x * a + bb; o.y = v.y * a + bb; o.z = v.z * a + bb; o.w = v.w * a + bb;
    *(float4*)(dst + (size_t)u * N_ + threadIdx.x * 4) = o;
  }
}

// ---------------------------------------------------------------------------
// Kernel 2: QKV GEMM.  out[b,n,o] = sum_c xn[b,c,n] * W[o,c]
// tile 128(m=n) x 128(o), K-step 16, 8x8 per thread (split-tile), scatter
// epilogue into q/k/v buffers laid out [bh][n][hd] with q,k pre-scaled.
// ---------------------------------------------------------------------------
__global__ __launch_bounds__(256, 3) void qkv_gemm(const float* __restrict__ xn,
                                                   const float* __restrict__ w,
                                                   float* __restrict__ qb,
                                                   float* __restrict__ kbf,
                                                   float* __restrict__ vbf) {
  __shared__ float As[16][128];
  __shared__ float Ws[16][132];
  int b = blockIdx.z, n0 = blockIdx.x * 128, o0 = blockIdx.y * 128;
  int tid = threadIdx.x;
  int tm = tid & 15, tn = tid >> 4;
  float acc[8][8] = {};
  int kkA = tid >> 4;
  int mgA = (tid & 15) * 4;
  int ooW = tid >> 1;
  int k8  = (tid & 1) * 8;
  const float* Abase = xn + (size_t)b * C_ * N_ + n0;
  const float* Wbase = w + (size_t)(o0 + ooW) * C_;

  for (int c0 = 0; c0 < C_; c0 += 16) {
    float4 a0 = *(const float4*)(Abase + (size_t)(c0 + kkA) * N_ + mgA);
    float4 a1 = *(const float4*)(Abase + (size_t)(c0 + kkA) * N_ + mgA + 64);
    float4 w0 = *(const float4*)(Wbase + c0 + k8);
    float4 w1 = *(const float4*)(Wbase + c0 + k8 + 4);
    __syncthreads();
    *(float4*)&As[kkA][mgA]      = a0;
    *(float4*)&As[kkA][mgA + 64] = a1;
    Ws[k8 + 0][ooW] = w0.x; Ws[k8 + 1][ooW] = w0.y;
    Ws[k8 + 2][ooW] = w0.z; Ws[k8 + 3][ooW] = w0.w;
    Ws[k8 + 4][ooW] = w1.x; Ws[k8 + 5][ooW] = w1.y;
    Ws[k8 + 6][ooW] = w1.z; Ws[k8 + 7][ooW] = w1.w;
    __syncthreads();
#pragma unroll
    for (int kk = 0; kk < 16; ++kk) {
      float4 x0 = *(const float4*)&As[kk][tm * 4];
      float4 x1 = *(const float4*)&As[kk][tm * 4 + 64];
      float4 y0 = *(const float4*)&Ws[kk][tn * 4];
      float4 y1 = *(const float4*)&Ws[kk][tn * 4 + 64];
      float av[8] = {x0.x, x0.y, x0.z, x0.w, x1.x, x1.y, x1.z, x1.w};
      float wv[8] = {y0.x, y0.y, y0.z, y0.w, y1.x, y1.y, y1.z, y1.w};
#pragma unroll
      for (int i = 0; i < 8; ++i)
#pragma unroll
        for (int j = 0; j < 8; ++j) acc[i][j] = fmaf(av[i], wv[j], acc[i][j]);
    }
  }

  const float scale = 0.35355339059327373f;  // 64^(-1/4)
#pragma unroll
  for (int i = 0; i < 8; ++i) {
    int n = n0 + tm * 4 + (i & 3) + (i >> 2) * 64;
#pragma unroll
    for (int jg = 0; jg < 2; ++jg) {
      int ob = o0 + tn * 4 + jg * 64;
      int head = ob / 192;
      int r = ob - head * 192;
      float4 vv;
      vv.x = acc[i][jg * 4 + 0]; vv.y = acc[i][jg * 4 + 1];
      vv.z = acc[i][jg * 4 + 2]; vv.w = acc[i][jg * 4 + 3];
      size_t rowbase = ((size_t)(b * NH_ + head) * N_ + n) * HD_;
      if (r < 64) {
        vv.x *= scale; vv.y *= scale; vv.z *= scale; vv.w *= scale;
        *(float4*)(qb + rowbase + r) = vv;
      } else if (r < 128) {
        vv.x *= scale; vv.y *= scale; vv.z *= scale; vv.w *= scale;
        *(float4*)(kbf + rowbase + (r - 64)) = vv;
      } else {
        *(float4*)(vbf + rowbase + (r - 128)) = vv;
      }
    }
  }
}

// ---------------------------------------------------------------------------
// Kernel 3: attention, flash-style, lane = one query row (half of hd).
// 2 lanes per row (hf = c-half), online softmax with defer-max (T13).
// K/V streamed from global (L2-resident per head), 1-deep K prefetch.
// Writes h into hb laid out (B, N, C).
// ---------------------------------------------------------------------------
__global__ __launch_bounds__(256, 2) void attn_kernel(const float* __restrict__ qb,
                                                      const float* __restrict__ kb,
                                                      const float* __restrict__ vb,
                                                      float* __restrict__ hb) {
  int bh = blockIdx.y;
  int t  = blockIdx.x * 128 + (threadIdx.x >> 1);
  int hf = threadIdx.x & 1;
  const float* qp = qb + (((size_t)bh << 10) + t) * HD_ + hf * 32;
  const float* kp = kb + (((size_t)bh << 10)) * HD_ + hf * 32;
  const float* vp = vb + (((size_t)bh << 10)) * HD_ + hf * 32;

  float4 qs[8], h4[8], kc[8], kn[8], vc[8];
#pragma unroll
  for (int u = 0; u < 8; ++u) {
    qs[u] = *(const float4*)(qp + u * 4);
    h4[u].x = 0.f; h4[u].y = 0.f; h4[u].z = 0.f; h4[u].w = 0.f;
  }
#pragma unroll
  for (int u = 0; u < 8; ++u) kc[u] = *(const float4*)(kp + u * 4);

  float m = -INFINITY, l = 0.f;
  for (int s = 0; s < N_; ++s) {
    int sn = (s + 1 < N_) ? s + 1 : s;
#pragma unroll
    for (int u = 0; u < 8; ++u) kn[u] = *(const float4*)(kp + (size_t)sn * HD_ + u * 4);
#pragma unroll
    for (int u = 0; u < 8; ++u) vc[u] = *(const float4*)(vp + (size_t)s * HD_ + u * 4);

    float p0 = 0.f, p1 = 0.f, p2 = 0.f, p3 = 0.f;
#pragma unroll
    for (int u = 0; u < 8; ++u) {
      p0 = fmaf(qs[u].x, kc[u].x, p0);
      p1 = fmaf(qs[u].y, kc[u].y, p1);
      p2 = fmaf(qs[u].z, kc[u].z, p2);
      p3 = fmaf(qs[u].w, kc[u].w, p3);
    }
    float sc = (p0 + p1) + (p2 + p3);
    sc += __shfl_xor(sc, 1);

    if (sc > m + 8.0f) {           // defer-max: rescale only on big jumps
      float corr = __expf(m - sc);
      l *= corr;
#pragma unroll
      for (int u = 0; u < 8; ++u) {
        h4[u].x *= corr; h4[u].y *= corr; h4[u].z *= corr; h4[u].w *= corr;
      }
      m = sc;
    }
    float p = __expf(sc - m);
    l += p;
#pragma unroll
    for (int u = 0; u < 8; ++u) {
      h4[u].x = fmaf(p, vc[u].x, h4[u].x);
      h4[u].y = fmaf(p, vc[u].y, h4[u].y);
      h4[u].z = fmaf(p, vc[u].z, h4[u].z);
      h4[u].w = fmaf(p, vc[u].w, h4[u].w);
    }
#pragma unroll
    for (int u = 0; u < 8; ++u) kc[u] = kn[u];
  }

  float inv = 1.0f / l;
  int b = bh >> 3, head = bh & 7;
  float* dst = hb + ((size_t)b * N_ + t) * C_ + head * HD_ + hf * 32;
#pragma unroll
  for (int u = 0; u < 8; ++u) {
    float4 o;
    o.x = h4[u].x * inv; o.y = h4[u].y * inv; o.z = h4[u].z * inv; o.w = h4[u].w * inv;
    *(float4*)(dst + u * 4) = o;
  }
}

// ---------------------------------------------------------------------------
// Kernel 4: proj GEMM + bias + residual.
// out[b,o,n] = sum_c hb[b,n,c]*W[o,c] + bias[o] + x[b,o,n]
// tile 64(m=n) x 128(o), K-step 16, 4x8 per thread.
// ---------------------------------------------------------------------------
__global__ __launch_bounds__(256, 2) void proj_gemm(const float* __restrict__ hb,
                                                    const float* __restrict__ w,
                                                    const float* __restrict__ bias,
                                                    const float* __restrict__ x,
                                                    float* __restrict__ out) {
  __shared__ float As[16][64];
  __shared__ float Ws[16][132];
  int b = blockIdx.z, n0 = blockIdx.x * 64, o0 = blockIdx.y * 128;
  int tid = threadIdx.x;
  int tm = tid & 15, tn = tid >> 4;
  float acc[4][8] = {};
  int mmA = tid >> 2;
  int k4  = (tid & 3) * 4;
  int ooW = tid >> 1;
  int k8  = (tid & 1) * 8;
  const float* Abase = hb + (size_t)b * N_ * C_;
  const float* Wbase = w + (size_t)(o0 + ooW) * C_;

  for (int c0 = 0; c0 < C_; c0 += 16) {
    float4 a0 = *(const float4*)(Abase + (size_t)(n0 + mmA) * C_ + c0 + k4);
    float4 w0 = *(const float4*)(Wbase + c0 + k8);
    float4 w1 = *(const float4*)(Wbase + c0 + k8 + 4);
    __syncthreads();
    As[k4 + 0][mmA] = a0.x; As[k4 + 1][mmA] = a0.y;
    As[k4 + 2][mmA] = a0.z; As[k4 + 3][mmA] = a0.w;
    Ws[k8 + 0][ooW] = w0.x; Ws[k8 + 1][ooW] = w0.y;
    Ws[k8 + 2][ooW] = w0.z; Ws[k8 + 3][ooW] = w0.w;
    Ws[k8 + 4][ooW] = w1.x; Ws[k8 + 5][ooW] = w1.y;
    Ws[k8 + 6][ooW] = w1.z; Ws[k8 + 7][ooW] = w1.w;
    __syncthreads();
#pragma unroll
    for (int kk = 0; kk < 16; ++kk) {
      float4 xa = *(const float4*)&As[kk][tm * 4];
      float4 y0 = *(const float4*)&Ws[kk][tn * 4];
      float4 y1 = *(const float4*)&Ws[kk][tn * 4 + 64];
      float av[4] = {xa.x, xa.y, xa.z, xa.w};
      float wv[8] = {y0.x, y0.y, y0.z, y0.w, y1.x, y1.y, y1.z, y1.w};
#pragma unroll
      for (int i = 0; i < 4; ++i)
#pragma unroll
        for (int j = 0; j < 8; ++j) acc[i][j] = fmaf(av[i], wv[j], acc[i][j]);
    }
  }

  int n4 = n0 + tm * 4;
#pragma unroll
  for (int jg = 0; jg < 2; ++jg) {
#pragma unroll
    for (int jj = 0; jj < 4; ++jj) {
      int o = o0 + tn * 4 + jg * 64 + jj;
      float bo = bias[o];
      const float* xr = x + ((size_t)b * C_ + o) * N_ + n4;
      float4 xv = *(const float4*)xr;
      float4 r;
      r.x = acc[0][jg * 4 + jj] + bo + xv.x;
      r.y = acc[1][jg * 4 + jj] + bo + xv.y;
      r.z = acc[2][jg * 4 + jj] + bo + xv.z;
      r.w = acc[3][jg * 4 + jj] + bo + xv.w;
      *(float4*)(out + ((size_t)b * C_ + o) * N_ + n4) = r;
    }
  }
}

// ---------------------------------------------------------------------------
extern "C" void kernel_launch(void* const* d_in, const int* in_sizes, int n_in,
                              void* d_out, int out_size, void* d_ws, size_t ws_size,
                              hipStream_t stream) {
  const float* x      = (const float*)d_in[0];
  const float* norm_w = (const float*)d_in[1];
  const float* norm_b = (const float*)d_in[2];
  const float* qkv_w  = (const float*)d_in[3];
  const float* proj_w = (const float*)d_in[4];
  const float* proj_b = (const float*)d_in[5];
  float* out = (float*)d_out;

  const size_t SZ = (size_t)B_ * C_ * N_;  // 4194304 floats
  float* xn = (float*)d_ws;                // also reused as hbuf after qkv
  float* qb = xn + SZ;
  float* kb = qb + SZ;
  float* vb = kb + SZ;

  gn_kernel<<<256, 256, 0, stream>>>(x, norm_w, norm_b, xn);
  qkv_gemm<<<dim3(8, 12, 8), 256, 0, stream>>>(xn, qkv_w, qb, kb, vb);
  attn_kernel<<<dim3(8, 64), 256, 0, stream>>>(qb, kb, vb, xn /* hbuf */);
  proj_gemm<<<dim3(16, 4, 8), 256, 0, stream>>>(xn, proj_w, proj_b, x, out);
}

// Round 3
// 583.110 us; speedup vs baseline: 3.6366x; 3.6366x over previous
//
#include <hip/hip_runtime.h>
#include <cstdint>
#include <cstddef>

#define B_   8
#define C_   512
#define N_   1024   // H*W
#define NH_  8
#define HD_  64
#define G_   32
#define CPG_ 16     // C_/G_

// ---------------------------------------------------------------------------
// Kernel 1: GroupNorm  (one block per (b, group)); writes xn in (B, C, N)
// ---------------------------------------------------------------------------
__global__ __launch_bounds__(256) void gn_kernel(const float* __restrict__ x,
                                                 const float* __restrict__ gw,
                                                 const float* __restrict__ gb,
                                                 float* __restrict__ xn) {
  int bid = blockIdx.x;
  int b = bid >> 5, g = bid & 31;
  const float* base = x + ((size_t)b * C_ + (size_t)g * CPG_) * N_;
  float4 vals[16];
  float4 s4 = {0.f, 0.f, 0.f, 0.f}, q4 = {0.f, 0.f, 0.f, 0.f};
#pragma unroll
  for (int u = 0; u < 16; ++u) {
    float4 v = *(const float4*)(base + (size_t)u * N_ + threadIdx.x * 4);
    vals[u] = v;
    s4.x += v.x; s4.y += v.y; s4.z += v.z; s4.w += v.w;
    q4.x += v.x * v.x; q4.y += v.y * v.y; q4.z += v.z * v.z; q4.w += v.w * v.w;
  }
  float s = (s4.x + s4.y) + (s4.z + s4.w);
  float q = (q4.x + q4.y) + (q4.z + q4.w);
#pragma unroll
  for (int off = 32; off; off >>= 1) {
    s += __shfl_xor(s, off);
    q += __shfl_xor(q, off);
  }
  __shared__ float sm[4], sq[4];
  __shared__ float smean, srstd;
  int wid = threadIdx.x >> 6;
  if ((threadIdx.x & 63) == 0) { sm[wid] = s; sq[wid] = q; }
  __syncthreads();
  if (threadIdx.x == 0) {
    float S = (sm[0] + sm[1]) + (sm[2] + sm[3]);
    float Q = (sq[0] + sq[1]) + (sq[2] + sq[3]);
    float mean = S * (1.0f / 16384.0f);
    float var  = Q * (1.0f / 16384.0f) - mean * mean;
    smean = mean;
    srstd = rsqrtf(var + 1e-5f);
  }
  __syncthreads();
  float mean = smean, rstd = srstd;
  float* dst = xn + ((size_t)b * C_ + (size_t)g * CPG_) * N_;
#pragma unroll
  for (int u = 0; u < 16; ++u) {
    int c = g * CPG_ + u;
    float a  = rstd * gw[c];
    float bb = gb[c] - mean * a;
    float4 v = vals[u];
    float4 o;
    o.x = v.x * a + bb; o.y = v.y * a + bb; o.z = v.z * a + bb; o.w = v.w * a + bb;
    *(float4*)(dst + (size_t)u * N_ + threadIdx.x * 4) = o;
  }
}

// ---------------------------------------------------------------------------
// Kernel 2: QKV GEMM.  out[b,n,o] = sum_c xn[b,c,n] * W[o,c]
// tile 128(m=n) x 128(o), K-step 16, 8x8 per thread.
// Epilogue layouts for the attention kernel's transpose-free staging:
//   q,k: k-major  [bh][hd][n]   (pre-scaled by 64^-0.25)
//   v:   n-major  [bh][n][hd]
// ---------------------------------------------------------------------------
__global__ __launch_bounds__(256, 3) void qkv_gemm(const float* __restrict__ xn,
                                                   const float* __restrict__ w,
                                                   float* __restrict__ qb,
                                                   float* __restrict__ kbf,
                                                   float* __restrict__ vbf) {
  __shared__ float As[16][128];
  __shared__ float Ws[16][132];
  int b = blockIdx.z, n0 = blockIdx.x * 128, o0 = blockIdx.y * 128;
  int tid = threadIdx.x;
  int tm = tid & 15, tn = tid >> 4;
  float acc[8][8] = {};
  int kkA = tid >> 4;
  int mgA = (tid & 15) * 4;
  int ooW = tid >> 1;
  int k8  = (tid & 1) * 8;
  const float* Abase = xn + (size_t)b * C_ * N_ + n0;
  const float* Wbase = w + (size_t)(o0 + ooW) * C_;

  for (int c0 = 0; c0 < C_; c0 += 16) {
    float4 a0 = *(const float4*)(Abase + (size_t)(c0 + kkA) * N_ + mgA);
    float4 a1 = *(const float4*)(Abase + (size_t)(c0 + kkA) * N_ + mgA + 64);
    float4 w0 = *(const float4*)(Wbase + c0 + k8);
    float4 w1 = *(const float4*)(Wbase + c0 + k8 + 4);
    __syncthreads();
    *(float4*)&As[kkA][mgA]      = a0;
    *(float4*)&As[kkA][mgA + 64] = a1;
    Ws[k8 + 0][ooW] = w0.x; Ws[k8 + 1][ooW] = w0.y;
    Ws[k8 + 2][ooW] = w0.z; Ws[k8 + 3][ooW] = w0.w;
    Ws[k8 + 4][ooW] = w1.x; Ws[k8 + 5][ooW] = w1.y;
    Ws[k8 + 6][ooW] = w1.z; Ws[k8 + 7][ooW] = w1.w;
    __syncthreads();
#pragma unroll
    for (int kk = 0; kk < 16; ++kk) {
      float4 x0 = *(const float4*)&As[kk][tm * 4];
      float4 x1 = *(const float4*)&As[kk][tm * 4 + 64];
      float4 y0 = *(const float4*)&Ws[kk][tn * 4];
      float4 y1 = *(const float4*)&Ws[kk][tn * 4 + 64];
      float av[8] = {x0.x, x0.y, x0.z, x0.w, x1.x, x1.y, x1.z, x1.w};
      float wv[8] = {y0.x, y0.y, y0.z, y0.w, y1.x, y1.y, y1.z, y1.w};
#pragma unroll
      for (int i = 0; i < 8; ++i)
#pragma unroll
        for (int j = 0; j < 8; ++j) acc[i][j] = fmaf(av[i], wv[j], acc[i][j]);
    }
  }

  const float scale = 0.35355339059327373f;  // 64^(-1/4)
#pragma unroll
  for (int jg = 0; jg < 2; ++jg) {
    int ob = o0 + tn * 4 + jg * 64;
    int head = ob / 192;
    int r0 = ob - head * 192;       // 0..191, multiple of 4; j-run stays in kind
    int kind = r0 >> 6;             // 0=q, 1=k, 2=v
    int hd0 = r0 & 63;
    size_t bhbase = (size_t)(b * NH_ + head) * ((size_t)HD_ * N_);
    if (kind < 2) {
      float* buf = kind ? kbf : qb;
      size_t base = bhbase + (size_t)hd0 * N_ + n0 + tm * 4;
#pragma unroll
      for (int j = 0; j < 4; ++j) {
        float4 lo, hi;
        lo.x = acc[0][jg*4+j] * scale; lo.y = acc[1][jg*4+j] * scale;
        lo.z = acc[2][jg*4+j] * scale; lo.w = acc[3][jg*4+j] * scale;
        hi.x = acc[4][jg*4+j] * scale; hi.y = acc[5][jg*4+j] * scale;
        hi.z = acc[6][jg*4+j] * scale; hi.w = acc[7][jg*4+j] * scale;
        *(float4*)(buf + base + (size_t)j * N_)      = lo;
        *(float4*)(buf + base + (size_t)j * N_ + 64) = hi;
      }
    } else {
#pragma unroll
      for (int i = 0; i < 8; ++i) {
        int n = n0 + tm * 4 + (i & 3) + (i >> 2) * 64;
        float4 vv;
        vv.x = acc[i][jg*4+0]; vv.y = acc[i][jg*4+1];
        vv.z = acc[i][jg*4+2]; vv.w = acc[i][jg*4+3];
        *(float4*)(vbf + bhbase + (size_t)n * HD_ + hd0) = vv;
      }
    }
  }
}

// ---------------------------------------------------------------------------
// Kernel 3: flash attention, fp32, 64(q) x 64(s) tiles, 4x4 register tiles.
//   GEMM1: S = Q·K^T from Qs[k][q], Ks[k][s] (both k-major, transpose-free)
//   softmax: online, row-stats via 16-lane shfl_xor reduce
//   GEMM2: O += P·V from Ps[s][q] (XOR-swizzled), Vs[s][hd]
// Next K/V tiles prefetched to registers during compute (T14).
// Grid (bh, qt): bh fastest -> all q-tiles of a head on one XCD (T1).
// ---------------------------------------------------------------------------
__global__ __launch_bounds__(256, 2) void attn_kernel(const float* __restrict__ qb,
                                                      const float* __restrict__ kb,
                                                      const float* __restrict__ vb,
                                                      float* __restrict__ hb) {
  __shared__ float Qs[64][64];
  __shared__ float Ks[64][64];
  __shared__ float Vs[64][64];
  __shared__ float Ps[64][64];
  int bh = blockIdx.x;            // 0..63
  int q0 = blockIdx.y * 64;       // q-tile origin
  int tid = threadIdx.x;
  int tm = tid >> 4, tn = tid & 15;

  const float* Qg = qb + ((size_t)bh << 16);   // [hd][1024]
  const float* Kg = kb + ((size_t)bh << 16);   // [hd][1024]
  const float* Vg = vb + ((size_t)bh << 16);   // [n][64]

  int sr = tid >> 4;              // staging row group
  int sc = (tid & 15) * 4;        // staging col

  // stage Q tile once: Qs[kd][q]
#pragma unroll
  for (int f = 0; f < 4; ++f) {
    float4 v = *(const float4*)(Qg + (size_t)(sr + 16 * f) * N_ + q0 + sc);
    *(float4*)&Qs[sr + 16 * f][sc] = v;
  }
  // prologue: K0/V0 via regs
  float4 kreg[4], vreg[4];
#pragma unroll
  for (int f = 0; f < 4; ++f) {
    kreg[f] = *(const float4*)(Kg + (size_t)(sr + 16 * f) * N_ + sc);
    vreg[f] = *(const float4*)(Vg + (size_t)(sr + 16 * f) * HD_ + sc);
  }
#pragma unroll
  for (int f = 0; f < 4; ++f) {
    *(float4*)&Ks[sr + 16 * f][sc] = kreg[f];
    *(float4*)&Vs[sr + 16 * f][sc] = vreg[f];
  }

  float S[4][4];
  float O[4][4] = {};
  float mrow[4] = {-3.0e38f, -3.0e38f, -3.0e38f, -3.0e38f};
  float lrow[4] = {};

  for (int st = 0; st < 16; ++st) {
    __syncthreads();                       // Ks,Vs(st) visible to all
    if (st < 15) {                         // prefetch next K/V tiles to regs
      int s0n = (st + 1) * 64;
#pragma unroll
      for (int f = 0; f < 4; ++f) {
        kreg[f] = *(const float4*)(Kg + (size_t)(sr + 16 * f) * N_ + s0n + sc);
        vreg[f] = *(const float4*)(Vg + (size_t)(s0n + sr + 16 * f) * HD_ + sc);
      }
    }
    // GEMM1: S[i][j] = sum_k Qs[k][tm*4+i] * Ks[k][tn*4+j]
#pragma unroll
    for (int i = 0; i < 4; ++i)
#pragma unroll
      for (int j = 0; j < 4; ++j) S[i][j] = 0.f;
#pragma unroll 8
    for (int k = 0; k < 64; ++k) {
      float4 a  = *(const float4*)&Qs[k][tm * 4];
      float4 b4 = *(const float4*)&Ks[k][tn * 4];
      float av[4] = {a.x, a.y, a.z, a.w};
      float bv[4] = {b4.x, b4.y, b4.z, b4.w};
#pragma unroll
      for (int i = 0; i < 4; ++i)
#pragma unroll
        for (int j = 0; j < 4; ++j) S[i][j] = fmaf(av[i], bv[j], S[i][j]);
    }
    // online softmax, per q-row
#pragma unroll
    for (int i = 0; i < 4; ++i) {
      float mx = fmaxf(fmaxf(S[i][0], S[i][1]), fmaxf(S[i][2], S[i][3]));
#pragma unroll
      for (int off = 8; off; off >>= 1) mx = fmaxf(mx, __shfl_xor(mx, off));
      float mnew = fmaxf(mrow[i], mx);
      float corr = __expf(mrow[i] - mnew);
      mrow[i] = mnew;
      float rs = 0.f;
#pragma unroll
      for (int j = 0; j < 4; ++j) {
        S[i][j] = __expf(S[i][j] - mnew);
        rs += S[i][j];
      }
#pragma unroll
      for (int off = 8; off; off >>= 1) rs += __shfl_xor(rs, off);
      lrow[i] = lrow[i] * corr + rs;
#pragma unroll
      for (int j = 0; j < 4; ++j) O[i][j] *= corr;
    }
    __syncthreads();                       // GEMM1 done by all: Ks free; Ps(prev) free
    // write P transposed+swizzled: Ps[s][q^swz]
#pragma unroll
    for (int j = 0; j < 4; ++j) {
      int s = tn * 4 + j;
      int colsw = (tm * 4) ^ (((s >> 2) & 7) << 2);
      float4 pv = {S[0][j], S[1][j], S[2][j], S[3][j]};
      *(float4*)&Ps[s][colsw] = pv;
    }
    if (st < 15) {                         // K(st+1) into LDS (Ks free now)
#pragma unroll
      for (int f = 0; f < 4; ++f) *(float4*)&Ks[sr + 16 * f][sc] = kreg[f];
    }
    __syncthreads();                       // Ps visible
    // GEMM2: O[i][j] += sum_s Ps[s][tm*4+i] * Vs[s][tn*4+j]
#pragma unroll 8
    for (int s = 0; s < 64; ++s) {
      int colsw = (tm * 4) ^ (((s >> 2) & 7) << 2);
      float4 a  = *(const float4*)&Ps[s][colsw];
      float4 b4 = *(const float4*)&Vs[s][tn * 4];
      float av[4] = {a.x, a.y, a.z, a.w};
      float bv[4] = {b4.x, b4.y, b4.z, b4.w};
#pragma unroll
      for (int i = 0; i < 4; ++i)
#pragma unroll
        for (int j = 0; j < 4; ++j) O[i][j] = fmaf(av[i], bv[j], O[i][j]);
    }
    __syncthreads();                       // GEMM2 done by all: Vs free
    if (st < 15) {
#pragma unroll
      for (int f = 0; f < 4; ++f) *(float4*)&Vs[sr + 16 * f][sc] = vreg[f];
    }
  }
  // epilogue: O / l -> hb[b][n][c]
  int b = bh >> 3, head = bh & 7;
#pragma unroll
  for (int i = 0; i < 4; ++i) {
    float inv = 1.0f / lrow[i];
    int n = q0 + tm * 4 + i;
    float4 o4 = {O[i][0] * inv, O[i][1] * inv, O[i][2] * inv, O[i][3] * inv};
    *(float4*)(hb + ((size_t)b * N_ + n) * C_ + head * HD_ + tn * 4) = o4;
  }
}

// ---------------------------------------------------------------------------
// Kernel 4: proj GEMM + bias + residual.
// out[b,o,n] = sum_c hb[b,n,c]*W[o,c] + bias[o] + x[b,o,n]
// ---------------------------------------------------------------------------
__global__ __launch_bounds__(256, 2) void proj_gemm(const float* __restrict__ hb,
                                                    const float* __restrict__ w,
                                                    const float* __restrict__ bias,
                                                    const float* __restrict__ x,
                                                    float* __restrict__ out) {
  __shared__ float As[16][64];
  __shared__ float Ws[16][132];
  int b = blockIdx.z, n0 = blockIdx.x * 64, o0 = blockIdx.y * 128;
  int tid = threadIdx.x;
  int tm = tid & 15, tn = tid >> 4;
  float acc[4][8] = {};
  int mmA = tid >> 2;
  int k4  = (tid & 3) * 4;
  int ooW = tid >> 1;
  int k8  = (tid & 1) * 8;
  const float* Abase = hb + (size_t)b * N_ * C_;
  const float* Wbase = w + (size_t)(o0 + ooW) * C_;

  for (int c0 = 0; c0 < C_; c0 += 16) {
    float4 a0 = *(const float4*)(Abase + (size_t)(n0 + mmA) * C_ + c0 + k4);
    float4 w0 = *(const float4*)(Wbase + c0 + k8);
    float4 w1 = *(const float4*)(Wbase + c0 + k8 + 4);
    __syncthreads();
    As[k4 + 0][mmA] = a0.x; As[k4 + 1][mmA] = a0.y;
    As[k4 + 2][mmA] = a0.z; As[k4 + 3][mmA] = a0.w;
    Ws[k8 + 0][ooW] = w0.x; Ws[k8 + 1][ooW] = w0.y;
    Ws[k8 + 2][ooW] = w0.z; Ws[k8 + 3][ooW] = w0.w;
    Ws[k8 + 4][ooW] = w1.x; Ws[k8 + 5][ooW] = w1.y;
    Ws[k8 + 6][ooW] = w1.z; Ws[k8 + 7][ooW] = w1.w;
    __syncthreads();
#pragma unroll
    for (int kk = 0; kk < 16; ++kk) {
      float4 xa = *(const float4*)&As[kk][tm * 4];
      float4 y0 = *(const float4*)&Ws[kk][tn * 4];
      float4 y1 = *(const float4*)&Ws[kk][tn * 4 + 64];
      float av[4] = {xa.x, xa.y, xa.z, xa.w};
      float wv[8] = {y0.x, y0.y, y0.z, y0.w, y1.x, y1.y, y1.z, y1.w};
#pragma unroll
      for (int i = 0; i < 4; ++i)
#pragma unroll
        for (int j = 0; j < 8; ++j) acc[i][j] = fmaf(av[i], wv[j], acc[i][j]);
    }
  }

  int n4 = n0 + tm * 4;
#pragma unroll
  for (int jg = 0; jg < 2; ++jg) {
#pragma unroll
    for (int jj = 0; jj < 4; ++jj) {
      int o = o0 + tn * 4 + jg * 64 + jj;
      float bo = bias[o];
      const float* xr = x + ((size_t)b * C_ + o) * N_ + n4;
      float4 xv = *(const float4*)xr;
      float4 r;
      r.x = acc[0][jg * 4 + jj] + bo + xv.x;
      r.y = acc[1][jg * 4 + jj] + bo + xv.y;
      r.z = acc[2][jg * 4 + jj] + bo + xv.z;
      r.w = acc[3][jg * 4 + jj] + bo + xv.w;
      *(float4*)(out + ((size_t)b * C_ + o) * N_ + n4) = r;
    }
  }
}

// ---------------------------------------------------------------------------
extern "C" void kernel_launch(void* const* d_in, const int* in_sizes, int n_in,
                              void* d_out, int out_size, void* d_ws, size_t ws_size,
                              hipStream_t stream) {
  const float* x      = (const float*)d_in[0];
  const float* norm_w = (const float*)d_in[1];
  const float* norm_b = (const float*)d_in[2];
  const float* qkv_w  = (const float*)d_in[3];
  const float* proj_w = (const float*)d_in[4];
  const float* proj_b = (const float*)d_in[5];
  float* out = (float*)d_out;

  const size_t SZ = (size_t)B_ * C_ * N_;  // 4194304 floats
  float* xn = (float*)d_ws;                // reused as hbuf after qkv
  float* qb = xn + SZ;
  float* kb = qb + SZ;
  float* vb = kb + SZ;

  gn_kernel<<<256, 256, 0, stream>>>(x, norm_w, norm_b, xn);
  qkv_gemm<<<dim3(8, 12, 8), 256, 0, stream>>>(xn, qkv_w, qb, kb, vb);
  attn_kernel<<<dim3(64, 16), 256, 0, stream>>>(qb, kb, vb, xn /* hbuf */);
  proj_gemm<<<dim3(16, 4, 8), 256, 0, stream>>>(xn, proj_w, proj_b, x, out);
}

// Round 7
// 340.820 us; speedup vs baseline: 6.2219x; 1.7109x over previous
//
#include <hip/hip_runtime.h>
#include <cstdint>
#include <cstddef>

#define B_   8
#define C_   512
#define N_   1024   // H*W
#define NH_  8
#define HD_  64
#define G_   32
#define CPG_ 16     // C_/G_

typedef __attribute__((ext_vector_type(8))) __bf16 bf16x8;
typedef __attribute__((ext_vector_type(4))) float f32x4;

#if __has_builtin(__builtin_amdgcn_exp2f)
#define EXP2(x) __builtin_amdgcn_exp2f(x)
#else
#define EXP2(x) exp2f(x)
#endif

__device__ __forceinline__ unsigned short f2bf(float f) {  // RNE fp32->bf16
  union { float f; unsigned int u; } c; c.f = f;
  return (unsigned short)((c.u + 0x7FFFu + ((c.u >> 16) & 1u)) >> 16);
}

__device__ __forceinline__ void* lds_at(void* base, int byte_off) {
  return (void*)((char*)base + byte_off);
}

// ---------------------------------------------------------------------------
// Kernel 1: GroupNorm  (one block per (b, group)); writes xn in (B, C, N) fp32
// ---------------------------------------------------------------------------
__global__ __launch_bounds__(256) void gn_kernel(const float* __restrict__ x,
                                                 const float* __restrict__ gw,
                                                 const float* __restrict__ gb,
                                                 float* __restrict__ xn) {
  int bid = blockIdx.x;
  int b = bid >> 5, g = bid & 31;
  const float* base = x + ((size_t)b * C_ + (size_t)g * CPG_) * N_;
  float4 vals[16];
  float4 s4 = {0.f, 0.f, 0.f, 0.f}, q4 = {0.f, 0.f, 0.f, 0.f};
#pragma unroll
  for (int u = 0; u < 16; ++u) {
    float4 v = *(const float4*)(base + (size_t)u * N_ + threadIdx.x * 4);
    vals[u] = v;
    s4.x += v.x; s4.y += v.y; s4.z += v.z; s4.w += v.w;
    q4.x += v.x * v.x; q4.y += v.y * v.y; q4.z += v.z * v.z; q4.w += v.w * v.w;
  }
  float s = (s4.x + s4.y) + (s4.z + s4.w);
  float q = (q4.x + q4.y) + (q4.z + q4.w);
#pragma unroll
  for (int off = 32; off; off >>= 1) {
    s += __shfl_xor(s, off);
    q += __shfl_xor(q, off);
  }
  __shared__ float sm[4], sq[4];
  __shared__ float smean, srstd;
  int wid = threadIdx.x >> 6;
  if ((threadIdx.x & 63) == 0) { sm[wid] = s; sq[wid] = q; }
  __syncthreads();
  if (threadIdx.x == 0) {
    float S = (sm[0] + sm[1]) + (sm[2] + sm[3]);
    float Q = (sq[0] + sq[1]) + (sq[2] + sq[3]);
    float mean = S * (1.0f / 16384.0f);
    float var  = Q * (1.0f / 16384.0f) - mean * mean;
    smean = mean;
    srstd = rsqrtf(var + 1e-5f);
  }
  __syncthreads();
  float mean = smean, rstd = srstd;
  float* dst = xn + ((size_t)b * C_ + (size_t)g * CPG_) * N_;
#pragma unroll
  for (int u = 0; u < 16; ++u) {
    int c = g * CPG_ + u;
    float a  = rstd * gw[c];
    float bb = gb[c] - mean * a;
    float4 v = vals[u];
    float4 o;
    o.x = v.x * a + bb; o.y = v.y * a + bb; o.z = v.z * a + bb; o.w = v.w * a + bb;
    *(float4*)(dst + (size_t)u * N_ + threadIdx.x * 4) = o;
  }
}

// ---------------------------------------------------------------------------
// Kernel 2: QKV GEMM (fp32 compute).  out[b,n,o] = sum_c xn[b,c,n] * W[o,c]
// Epilogue emits bf16 for the MFMA attention kernel:
//   q,k: [bh][n][hd] row-major, pre-scaled by hd^-0.25 * sqrt(log2(e))
//        (so attention softmax can use exp2 directly)
//   v:   [bh][hd][n] row-major (= V^T, the A-operand layout for O^T = V^T P^T)
// ---------------------------------------------------------------------------
__global__ __launch_bounds__(256, 3) void qkv_gemm(const float* __restrict__ xn,
                                                   const float* __restrict__ w,
                                                   unsigned short* __restrict__ qb,
                                                   unsigned short* __restrict__ kbf,
                                                   unsigned short* __restrict__ vbf) {
  __shared__ float As[16][128];
  __shared__ float Ws[16][132];
  int b = blockIdx.z, n0 = blockIdx.x * 128, o0 = blockIdx.y * 128;
  int tid = threadIdx.x;
  int tm = tid & 15, tn = tid >> 4;
  float acc[8][8] = {};
  int kkA = tid >> 4;
  int mgA = (tid & 15) * 4;
  int ooW = tid >> 1;
  int k8  = (tid & 1) * 8;
  const float* Abase = xn + (size_t)b * C_ * N_ + n0;
  const float* Wbase = w + (size_t)(o0 + ooW) * C_;

  for (int c0 = 0; c0 < C_; c0 += 16) {
    float4 a0 = *(const float4*)(Abase + (size_t)(c0 + kkA) * N_ + mgA);
    float4 a1 = *(const float4*)(Abase + (size_t)(c0 + kkA) * N_ + mgA + 64);
    float4 w0 = *(const float4*)(Wbase + c0 + k8);
    float4 w1 = *(const float4*)(Wbase + c0 + k8 + 4);
    __syncthreads();
    *(float4*)&As[kkA][mgA]      = a0;
    *(float4*)&As[kkA][mgA + 64] = a1;
    Ws[k8 + 0][ooW] = w0.x; Ws[k8 + 1][ooW] = w0.y;
    Ws[k8 + 2][ooW] = w0.z; Ws[k8 + 3][ooW] = w0.w;
    Ws[k8 + 4][ooW] = w1.x; Ws[k8 + 5][ooW] = w1.y;
    Ws[k8 + 6][ooW] = w1.z; Ws[k8 + 7][ooW] = w1.w;
    __syncthreads();
#pragma unroll
    for (int kk = 0; kk < 16; ++kk) {
      float4 x0 = *(const float4*)&As[kk][tm * 4];
      float4 x1 = *(const float4*)&As[kk][tm * 4 + 64];
      float4 y0 = *(const float4*)&Ws[kk][tn * 4];
      float4 y1 = *(const float4*)&Ws[kk][tn * 4 + 64];
      float av[8] = {x0.x, x0.y, x0.z, x0.w, x1.x, x1.y, x1.z, x1.w};
      float wv[8] = {y0.x, y0.y, y0.z, y0.w, y1.x, y1.y, y1.z, y1.w};
#pragma unroll
      for (int i = 0; i < 8; ++i)
#pragma unroll
        for (int j = 0; j < 8; ++j) acc[i][j] = fmaf(av[i], wv[j], acc[i][j]);
    }
  }

  // 64^-0.25 * sqrt(log2(e)) — folds both the attention scale and the
  // exp->exp2 conversion into q AND k symmetrically.
  const float qkscale = 0.4246609f;
#pragma unroll
  for (int jg = 0; jg < 2; ++jg) {
    int ob = o0 + tn * 4 + jg * 64;
    int head = ob / 192;
    int r0 = ob - head * 192;       // 0..191, multiple of 4; 4-run stays in kind
    int kind = r0 >> 6;             // 0=q, 1=k, 2=v
    int hd0 = r0 & 63;
    size_t bhbase = (size_t)(b * NH_ + head) * ((size_t)HD_ * N_);
    if (kind < 2) {
      unsigned short* buf = kind ? kbf : qb;
#pragma unroll
      for (int i = 0; i < 8; ++i) {
        int n = n0 + tm * 4 + (i & 3) + (i >> 2) * 64;
        ushort4 u;
        u.x = f2bf(acc[i][jg * 4 + 0] * qkscale);
        u.y = f2bf(acc[i][jg * 4 + 1] * qkscale);
        u.z = f2bf(acc[i][jg * 4 + 2] * qkscale);
        u.w = f2bf(acc[i][jg * 4 + 3] * qkscale);
        *(ushort4*)(buf + bhbase + (size_t)n * HD_ + hd0) = u;
      }
    } else {
#pragma unroll
      for (int jj = 0; jj < 4; ++jj)
#pragma unroll
        for (int ih = 0; ih < 2; ++ih) {
          int n = n0 + tm * 4 + ih * 64;
          ushort4 u;
          u.x = f2bf(acc[ih * 4 + 0][jg * 4 + jj]);
          u.y = f2bf(acc[ih * 4 + 1][jg * 4 + jj]);
          u.z = f2bf(acc[ih * 4 + 2][jg * 4 + jj]);
          u.w = f2bf(acc[ih * 4 + 3][jg * 4 + jj]);
          *(ushort4*)(vbf + bhbase + (size_t)(hd0 + jj) * N_ + n) = u;
        }
    }
  }
}

// ---------------------------------------------------------------------------
// Kernel 3: flash attention, bf16 MFMA (16x16x32), swapped-operand form.
//   S^T = K·Q   (A = K-rows [s][hd], B = Q [hd->q])  -> lane owns ONE q-column
//   softmax: scalar m/l per lane, 2 shuffles (xor 16, 32) per reduce
//   P^T -> LDS (wave-owned rows, XOR-swizzled), O^T = V^T·P^T
// K/V double-buffered in LDS; prefetch issued at tile top (T14); ONE
// __syncthreads per s-tile. LDS 40KB -> 4 blocks/CU.
// Grid (bh=64, qt=16): bh fastest => head b -> XCD b%8 every sweep (T1).
// ---------------------------------------------------------------------------
__global__ __launch_bounds__(256, 4) void attn_kernel(const unsigned short* __restrict__ qb,
                                                      const unsigned short* __restrict__ kb,
                                                      const unsigned short* __restrict__ vb,
                                                      float* __restrict__ hb) {
  __shared__ unsigned short Ks[2][4096];   // [s][hd] bf16, rows 128B, swizzled
  __shared__ unsigned short Vs[2][4096];   // [hd][s] bf16 (V^T), swizzled
  __shared__ unsigned short Ps[4096];      // [q][s]  bf16 (P^T), swizzled, wave-owned rows

  int bh = blockIdx.x;
  int q0 = blockIdx.y * 64;
  int tid = threadIdx.x;
  int w  = tid >> 6;          // wave id: owns q-cols q0 + w*16 .. +15
  int lr = tid & 15;          // lane%16
  int lg = (tid & 63) >> 4;   // lane/16 within wave
  int swz = (lr & 7) << 4;    // row-XOR swizzle for all frag reads (row ≡ lr mod 8)

  const unsigned short* Qg = qb + ((size_t)bh << 16);   // [n][hd]
  const unsigned short* Kg = kb + ((size_t)bh << 16);   // [n][hd]
  const unsigned short* Vg = vb + ((size_t)bh << 16);   // [hd][n]

  // Q B-frags held in registers for all 16 s-tiles: lane -> col q, k=8*lg+32t
  bf16x8 qf[2];
#pragma unroll
  for (int t = 0; t < 2; ++t)
    qf[t] = *(const bf16x8*)(Qg + (size_t)(q0 + w * 16 + lr) * HD_ + lg * 8 + t * 32);

  // staging geometry: thread covers chunks (r_p = tid>>3 + 32p, cc = tid&7)
  int cc = tid & 7;
  int r0s = tid >> 3;

  // prologue: stage tile 0
#pragma unroll
  for (int p = 0; p < 2; ++p) {
    int r = r0s + 32 * p;
    int4 kv = *(const int4*)(Kg + (size_t)r * HD_ + cc * 8);
    int4 vv = *(const int4*)(Vg + (size_t)r * N_ + cc * 8);
    *(int4*)lds_at(Ks[0], r * 128 + ((cc * 16) ^ ((r & 7) << 4))) = kv;
    *(int4*)lds_at(Vs[0], r * 128 + ((cc * 16) ^ ((r & 7) << 4))) = vv;
  }
  __syncthreads();

  f32x4 oacc[4] = {};
  float mrun = -1.0e30f, lrun = 0.f;

  for (int st = 0; st < 16; ++st) {
    int cur = st & 1, nxt = cur ^ 1;
    int4 kpre[2], vpre[2];
    if (st < 15) {                      // issue next-tile loads early (T14)
      int s0n = (st + 1) * 64;
#pragma unroll
      for (int p = 0; p < 2; ++p) {
        int r = r0s + 32 * p;
        kpre[p] = *(const int4*)(Kg + (size_t)(s0n + r) * HD_ + cc * 8);
        vpre[p] = *(const int4*)(Vg + (size_t)r * N_ + s0n + cc * 8);
      }
    }

    // ---- QK: S^T frags (s-rows 16f.., q-col = q0+w*16+lr) ----
    f32x4 sacc[4] = {};
#pragma unroll
    for (int t = 0; t < 2; ++t)
#pragma unroll
      for (int f = 0; f < 4; ++f) {
        bf16x8 ka = *(const bf16x8*)lds_at(Ks[cur],
                        (16 * f + lr) * 128 + ((lg * 16 + t * 64) ^ swz));
        sacc[f] = __builtin_amdgcn_mfma_f32_16x16x32_bf16(ka, qf[t], sacc[f], 0, 0, 0);
      }

    // ---- online softmax (exp2 domain; scale pre-folded into q,k) ----
    float mt = sacc[0][0];
#pragma unroll
    for (int f = 0; f < 4; ++f)
#pragma unroll
      for (int i = 0; i < 4; ++i) mt = fmaxf(mt, sacc[f][i]);
    mt = fmaxf(mt, __shfl_xor(mt, 16));
    mt = fmaxf(mt, __shfl_xor(mt, 32));
    float mnew = fmaxf(mrun, mt);
    float corr = EXP2(mrun - mnew);
    mrun = mnew;
    float psum = 0.f;
    int qrow = w * 16 + lr;
#pragma unroll
    for (int f = 0; f < 4; ++f) {       // P^T -> LDS, 4 bf16 (s=16f+4lg..+3) per write
      float p0 = EXP2(sacc[f][0] - mnew);
      float p1 = EXP2(sacc[f][1] - mnew);
      float p2 = EXP2(sacc[f][2] - mnew);
      float p3 = EXP2(sacc[f][3] - mnew);
      psum += (p0 + p1) + (p2 + p3);
      uint2 pw;
      pw.x = (unsigned int)f2bf(p0) | ((unsigned int)f2bf(p1) << 16);
      pw.y = (unsigned int)f2bf(p2) | ((unsigned int)f2bf(p3) << 16);
      *(uint2*)lds_at(Ps, qrow * 128 + ((32 * f + 8 * lg) ^ swz)) = pw;
    }
    psum += __shfl_xor(psum, 16);
    psum += __shfl_xor(psum, 32);
    lrun = lrun * corr + psum;
#pragma unroll
    for (int f = 0; f < 4; ++f)
#pragma unroll
      for (int i = 0; i < 4; ++i) oacc[f][i] *= corr;

    // ---- PV: O^T += V^T · P^T (Ps rows are wave-owned: no barrier) ----
    bf16x8 pfr[2];
#pragma unroll
    for (int t = 0; t < 2; ++t)
      pfr[t] = *(const bf16x8*)lds_at(Ps, qrow * 128 + ((lg * 16 + t * 64) ^ swz));
#pragma unroll
    for (int t = 0; t < 2; ++t)
#pragma unroll
      for (int f = 0; f < 4; ++f) {
        bf16x8 va = *(const bf16x8*)lds_at(Vs[cur],
                        (16 * f + lr) * 128 + ((lg * 16 + t * 64) ^ swz));
        oacc[f] = __builtin_amdgcn_mfma_f32_16x16x32_bf16(va, pfr[t], oacc[f], 0, 0, 0);
      }

    if (st < 15) {                      // write prefetched tile; ONE barrier/tile
#pragma unroll
      for (int p = 0; p < 2; ++p) {
        int r = r0s + 32 * p;
        *(int4*)lds_at(Ks[nxt], r * 128 + ((cc * 16) ^ ((r & 7) << 4))) = kpre[p];
        *(int4*)lds_at(Vs[nxt], r * 128 + ((cc * 16) ^ ((r & 7) << 4))) = vpre[p];
      }
      __syncthreads();
    }
  }

  // epilogue: O = O^T/l -> hb[b][n=q][c]  (fp32 for the proj GEMM)
  float inv = 1.0f / lrun;
  int q = q0 + w * 16 + lr;
  int b = bh >> 3, head = bh & 7;
  float* dst = hb + ((size_t)b * N_ + q) * C_ + head * HD_;
#pragma unroll
  for (int f = 0; f < 4; ++f) {
    float4 o4 = {oacc[f][0] * inv, oacc[f][1] * inv, oacc[f][2] * inv, oacc[f][3] * inv};
    *(float4*)(dst + 16 * f + 4 * lg) = o4;
  }
}

// ---------------------------------------------------------------------------
// Kernel 4: proj GEMM + bias + residual (fp32).
// out[b,o,n] = sum_c hb[b,n,c]*W[o,c] + bias[o] + x[b,o,n]
// ---------------------------------------------------------------------------
__global__ __launch_bounds__(256, 2) void proj_gemm(const float* __restrict__ hb,
                                                    const float* __restrict__ w,
                                                    const float* __restrict__ bias,
                                                    const float* __restrict__ x,
                                                    float* __restrict__ out) {
  __shared__ float As[16][64];
  __shared__ float Ws[16][132];
  int b = blockIdx.z, n0 = blockIdx.x * 64, o0 = blockIdx.y * 128;
  int tid = threadIdx.x;
  int tm = tid & 15, tn = tid >> 4;
  float acc[4][8] = {};
  int mmA = tid >> 2;
  int k4  = (tid & 3) * 4;
  int ooW = tid >> 1;
  int k8  = (tid & 1) * 8;
  const float* Abase = hb + (size_t)b * N_ * C_;
  const float* Wbase = w + (size_t)(o0 + ooW) * C_;

  for (int c0 = 0; c0 < C_; c0 += 16) {
    float4 a0 = *(const float4*)(Abase + (size_t)(n0 + mmA) * C_ + c0 + k4);
    float4 w0 = *(const float4*)(Wbase + c0 + k8);
    float4 w1 = *(const float4*)(Wbase + c0 + k8 + 4);
    __syncthreads();
    As[k4 + 0][mmA] = a0.x; As[k4 + 1][mmA] = a0.y;
    As[k4 + 2][mmA] = a0.z; As[k4 + 3][mmA] = a0.w;
    Ws[k8 + 0][ooW] = w0.x; Ws[k8 + 1][ooW] = w0.y;
    Ws[k8 + 2][ooW] = w0.z; Ws[k8 + 3][ooW] = w0.w;
    Ws[k8 + 4][ooW] = w1.x; Ws[k8 + 5][ooW] = w1.y;
    Ws[k8 + 6][ooW] = w1.z; Ws[k8 + 7][ooW] = w1.w;
    __syncthreads();
#pragma unroll
    for (int kk = 0; kk < 16; ++kk) {
      float4 xa = *(const float4*)&As[kk][tm * 4];
      float4 y0 = *(const float4*)&Ws[kk][tn * 4];
      float4 y1 = *(const float4*)&Ws[kk][tn * 4 + 64];
      float av[4] = {xa.x, xa.y, xa.z, xa.w};
      float wv[8] = {y0.x, y0.y, y0.z, y0.w, y1.x, y1.y, y1.z, y1.w};
#pragma unroll
      for (int i = 0; i < 4; ++i)
#pragma unroll
        for (int j = 0; j < 8; ++j) acc[i][j] = fmaf(av[i], wv[j], acc[i][j]);
    }
  }

  int n4 = n0 + tm * 4;
#pragma unroll
  for (int jg = 0; jg < 2; ++jg) {
#pragma unroll
    for (int jj = 0; jj < 4; ++jj) {
      int o = o0 + tn * 4 + jg * 64 + jj;
      float bo = bias[o];
      const float* xr = x + ((size_t)b * C_ + o) * N_ + n4;
      float4 xv = *(const float4*)xr;
      float4 r;
      r.x = acc[0][jg * 4 + jj] + bo + xv.x;
      r.y = acc[1][jg * 4 + jj] + bo + xv.y;
      r.z = acc[2][jg * 4 + jj] + bo + xv.z;
      r.w = acc[3][jg * 4 + jj] + bo + xv.w;
      *(float4*)(out + ((size_t)b * C_ + o) * N_ + n4) = r;
    }
  }
}

// ---------------------------------------------------------------------------
extern "C" void kernel_launch(void* const* d_in, const int* in_sizes, int n_in,
                              void* d_out, int out_size, void* d_ws, size_t ws_size,
                              hipStream_t stream) {
  const float* x      = (const float*)d_in[0];
  const float* norm_w = (const float*)d_in[1];
  const float* norm_b = (const float*)d_in[2];
  const float* qkv_w  = (const float*)d_in[3];
  const float* proj_w = (const float*)d_in[4];
  const float* proj_b = (const float*)d_in[5];
  float* out = (float*)d_out;

  // ws layout: [0,16MB) xn fp32 (reused as hb fp32 after qkv)
  //            [16MB,24MB) qb bf16, [24MB,32MB) kb bf16, [32MB,40MB) vb bf16
  float* xn = (float*)d_ws;
  unsigned short* qb = (unsigned short*)((char*)d_ws + (16u << 20));
  unsigned short* kb = (unsigned short*)((char*)d_ws + (24u << 20));
  unsigned short* vb = (unsigned short*)((char*)d_ws + (32u << 20));

  gn_kernel<<<256, 256, 0, stream>>>(x, norm_w, norm_b, xn);
  qkv_gemm<<<dim3(8, 12, 8), 256, 0, stream>>>(xn, qkv_w, qb, kb, vb);
  attn_kernel<<<dim3(64, 16), 256, 0, stream>>>(qb, kb, vb, xn /* hb */);
  proj_gemm<<<dim3(16, 4, 8), 256, 0, stream>>>(xn, proj_w, proj_b, x, out);
}

// Round 11
// 200.486 us; speedup vs baseline: 10.5771x; 1.7000x over previous
//
#include <hip/hip_runtime.h>
#include <cstdint>
#include <cstddef>

#define B_   8
#define C_   512
#define N_   1024   // H*W
#define NH_  8
#define HD_  64
#define G_   32
#define CPG_ 16     // C_/G_

typedef __attribute__((ext_vector_type(8))) __bf16 bf16x8;
typedef __attribute__((ext_vector_type(8))) _Float16 f16x8;
typedef __attribute__((ext_vector_type(4))) _Float16 f16x4;
typedef __attribute__((ext_vector_type(4))) float f32x4;

#if __has_builtin(__builtin_amdgcn_exp2f)
#define EXP2(x) __builtin_amdgcn_exp2f(x)
#else
#define EXP2(x) exp2f(x)
#endif

__device__ __forceinline__ unsigned short f2bf(float f) {  // RNE fp32->bf16
  union { float f; unsigned int u; } c; c.f = f;
  return (unsigned short)((c.u + 0x7FFFu + ((c.u >> 16) & 1u)) >> 16);
}

__device__ __forceinline__ void* lds_at(void* base, int byte_off) {
  return (void*)((char*)base + byte_off);
}

// ---------------------------------------------------------------------------
// Kernel 0: qkv_w fp32 -> fp16 (3MB -> 1.5MB), once per launch.
// ---------------------------------------------------------------------------
__global__ __launch_bounds__(256) void wcvt_kernel(const float* __restrict__ w,
                                                   _Float16* __restrict__ w16) {
  int i = (blockIdx.x * 256 + threadIdx.x) * 4;   // grid sized exactly
  float4 v = *(const float4*)(w + i);
  f16x4 h;
  h[0] = (_Float16)v.x; h[1] = (_Float16)v.y;
  h[2] = (_Float16)v.z; h[3] = (_Float16)v.w;
  *(f16x4*)(w16 + i) = h;
}

// ---------------------------------------------------------------------------
// Kernel 1: GroupNorm -> fp16 xn16 in TRANSPOSED layout [b][n][c].
// (n-major so the qkv MFMA kernel stages A/B tiles with coalesced rows.)
// ---------------------------------------------------------------------------
__global__ __launch_bounds__(256) void gn_kernel(const float* __restrict__ x,
                                                 const float* __restrict__ gw,
                                                 const float* __restrict__ gb,
                                                 _Float16* __restrict__ xn16) {
  int bid = blockIdx.x;
  int b = bid >> 5, g = bid & 31;
  const float* base = x + ((size_t)b * C_ + (size_t)g * CPG_) * N_;
  float4 vals[16];
  float4 s4 = {0.f, 0.f, 0.f, 0.f}, q4 = {0.f, 0.f, 0.f, 0.f};
#pragma unroll
  for (int u = 0; u < 16; ++u) {
    float4 v = *(const float4*)(base + (size_t)u * N_ + threadIdx.x * 4);
    vals[u] = v;
    s4.x += v.x; s4.y += v.y; s4.z += v.z; s4.w += v.w;
    q4.x += v.x * v.x; q4.y += v.y * v.y; q4.z += v.z * v.z; q4.w += v.w * v.w;
  }
  float s = (s4.x + s4.y) + (s4.z + s4.w);
  float q = (q4.x + q4.y) + (q4.z + q4.w);
#pragma unroll
  for (int off = 32; off; off >>= 1) {
    s += __shfl_xor(s, off);
    q += __shfl_xor(q, off);
  }
  __shared__ float sm[4], sq[4];
  __shared__ float smean, srstd;
  int wid = threadIdx.x >> 6;
  if ((threadIdx.x & 63) == 0) { sm[wid] = s; sq[wid] = q; }
  __syncthreads();
  if (threadIdx.x == 0) {
    float S = (sm[0] + sm[1]) + (sm[2] + sm[3]);
    float Q = (sq[0] + sq[1]) + (sq[2] + sq[3]);
    float mean = S * (1.0f / 16384.0f);
    float var  = Q * (1.0f / 16384.0f) - mean * mean;
    smean = mean;
    srstd = rsqrtf(var + 1e-5f);
  }
  __syncthreads();
  float mean = smean, rstd = srstd;
  float aa[16], bb2[16];
#pragma unroll
  for (int u = 0; u < 16; ++u) {
    int c = g * CPG_ + u;
    aa[u]  = rstd * gw[c];
    bb2[u] = gb[c] - mean * aa[u];
  }
#pragma unroll
  for (int i = 0; i < 4; ++i) {
    f16x8 lo, hi;
#pragma unroll
    for (int u = 0; u < 8; ++u)
      lo[u] = (_Float16)(((const float*)&vals[u])[i] * aa[u] + bb2[u]);
#pragma unroll
    for (int u = 0; u < 8; ++u)
      hi[u] = (_Float16)(((const float*)&vals[u + 8])[i] * aa[u + 8] + bb2[u + 8]);
    size_t dst = ((size_t)b * N_ + (size_t)(threadIdx.x * 4 + i)) * C_ + g * CPG_;
    *(f16x8*)(xn16 + dst)     = lo;
    *(f16x8*)(xn16 + dst + 8) = hi;
  }
}

// ---------------------------------------------------------------------------
// Kernel 2: QKV GEMM, fp16 MFMA (16x16x32_f16), swapped operands:
//   A = W16 rows (M = o), B = xn16 cols (N = n)  ->  D col = n, row = o.
// Tile 128(o) x 128(n), BK=64, 4 waves (2o x 2n), 4x4 frags/wave.
// Both LDS tiles [row][k] with 128B rows + (row&7)<<4 XOR swizzle; 1-barrier
// double-buffer (validated in attn). Epilogue -> bf16 q/k ([bh][n][hd],
// pre-scaled) and v ([bh][hd][n]); layouts unchanged for attn.
// ---------------------------------------------------------------------------
__global__ __launch_bounds__(256, 2) void qkv_gemm(const _Float16* __restrict__ xn16,
                                                   const _Float16* __restrict__ w16,
                                                   unsigned short* __restrict__ qb,
                                                   unsigned short* __restrict__ kbf,
                                                   unsigned short* __restrict__ vbf) {
  __shared__ _Float16 Wl[2][8192];   // [o:128][c:64] swizzled, 16KB each
  __shared__ _Float16 Xl[2][8192];   // [n:128][c:64] swizzled

  int ot = blockIdx.x;               // 0..11  (o-tile, fast index: W L2-hot)
  int nt = blockIdx.y;               // 0..63  (bn-tile)
  int tid = threadIdx.x;
  int lr = tid & 15;                 // lane%16
  int lg = (tid & 63) >> 4;          // lane/16 in wave
  int w  = tid >> 6;
  int wo = w >> 1, wn = w & 1;       // wave tile: 64o x 64n
  int o0 = ot * 128;
  int swz = (lr & 7) << 4;

  // staging geometry: thread -> (row = tid>>3 + 32p, chunk cc = tid&7)
  int cc = tid & 7;
  int r0 = tid >> 3;
  const _Float16* Wg = w16 + (size_t)o0 * C_;
  const _Float16* Xg = xn16 + (size_t)(nt * 128) * C_;

  // prologue: stage k-step 0
#pragma unroll
  for (int p = 0; p < 4; ++p) {
    int r = r0 + 32 * p;
    int4 wv = *(const int4*)(Wg + (size_t)r * C_ + cc * 8);
    int4 xv = *(const int4*)(Xg + (size_t)r * C_ + cc * 8);
    *(int4*)lds_at(Wl[0], r * 128 + ((cc * 16) ^ ((r & 7) << 4))) = wv;
    *(int4*)lds_at(Xl[0], r * 128 + ((cc * 16) ^ ((r & 7) << 4))) = xv;
  }
  __syncthreads();

  f32x4 acc[4][4] = {};

  for (int ks = 0; ks < 8; ++ks) {
    int cur = ks & 1, nxt = cur ^ 1;
    int4 wpre[4], xpre[4];
    if (ks < 7) {                    // issue next-K loads early (T14)
      int k0n = (ks + 1) * 64;
#pragma unroll
      for (int p = 0; p < 4; ++p) {
        int r = r0 + 32 * p;
        wpre[p] = *(const int4*)(Wg + (size_t)r * C_ + k0n + cc * 8);
        xpre[p] = *(const int4*)(Xg + (size_t)r * C_ + k0n + cc * 8);
      }
    }
    // compute: 2 k-slices x 16 MFMA
#pragma unroll
    for (int t = 0; t < 2; ++t) {
      f16x8 af[4], bf[4];
#pragma unroll
      for (int f = 0; f < 4; ++f)
        af[f] = *(const f16x8*)lds_at(Wl[cur],
                    (wo * 64 + f * 16 + lr) * 128 + ((t * 64 + lg * 16) ^ swz));
#pragma unroll
      for (int f = 0; f < 4; ++f)
        bf[f] = *(const f16x8*)lds_at(Xl[cur],
                    (wn * 64 + f * 16 + lr) * 128 + ((t * 64 + lg * 16) ^ swz));
#pragma unroll
      for (int fo = 0; fo < 4; ++fo)
#pragma unroll
        for (int fn = 0; fn < 4; ++fn)
          acc[fo][fn] = __builtin_amdgcn_mfma_f32_16x16x32_f16(af[fo], bf[fn],
                                                               acc[fo][fn], 0, 0, 0);
    }
    if (ks < 7) {                    // write prefetched tile; ONE barrier/step
#pragma unroll
      for (int p = 0; p < 4; ++p) {
        int r = r0 + 32 * p;
        *(int4*)lds_at(Wl[nxt], r * 128 + ((cc * 16) ^ ((r & 7) << 4))) = wpre[p];
        *(int4*)lds_at(Xl[nxt], r * 128 + ((cc * 16) ^ ((r & 7) << 4))) = xpre[p];
      }
      __syncthreads();
    }
  }

  // epilogue: D col = n (lr), rows o = lg*4+i per frag; -> bf16 q/k/v
  const float qkscale = 0.4246609f;  // 64^-0.25 * sqrt(log2(e))
#pragma unroll
  for (int fo = 0; fo < 4; ++fo) {
#pragma unroll
    for (int fn = 0; fn < 4; ++fn) {
      int ob4 = o0 + wo * 64 + fo * 16 + lg * 4;         // 4-run base (mod 4)
      int ngl = nt * 128 + wn * 64 + fn * 16 + lr;       // global bn row
      int b = ngl >> 10, n = ngl & 1023;
      int head = ob4 / 192;
      int r = ob4 - head * 192;
      int kind = r >> 6;             // 0=q, 1=k, 2=v
      int hd0 = r & 63;
      size_t bhbase = (size_t)(b * NH_ + head) * ((size_t)HD_ * N_);
      f32x4 a = acc[fo][fn];
      if (kind < 2) {
        unsigned short* buf = kind ? kbf : qb;
        ushort4 u;
        u.x = f2bf(a[0] * qkscale); u.y = f2bf(a[1] * qkscale);
        u.z = f2bf(a[2] * qkscale); u.w = f2bf(a[3] * qkscale);
        *(ushort4*)(buf + bhbase + (size_t)n * HD_ + hd0) = u;
      } else {
#pragma unroll
        for (int i = 0; i < 4; ++i)
          vbf[bhbase + (size_t)(hd0 + i) * N_ + n] = f2bf(a[i]);
      }
    }
  }
}

// ---------------------------------------------------------------------------
// Kernel 3: flash attention, bf16 MFMA (16x16x32), swapped-operand form.
// (unchanged from round 7 — validated)
// ---------------------------------------------------------------------------
__global__ __launch_bounds__(256, 4) void attn_kernel(const unsigned short* __restrict__ qb,
                                                      const unsigned short* __restrict__ kb,
                                                      const unsigned short* __restrict__ vb,
                                                      float* __restrict__ hb) {
  __shared__ unsigned short Ks[2][4096];   // [s][hd] bf16, rows 128B, swizzled
  __shared__ unsigned short Vs[2][4096];   // [hd][s] bf16 (V^T), swizzled
  __shared__ unsigned short Ps[4096];      // [q][s]  bf16 (P^T), wave-owned rows

  int bh = blockIdx.x;
  int q0 = blockIdx.y * 64;
  int tid = threadIdx.x;
  int w  = tid >> 6;
  int lr = tid & 15;
  int lg = (tid & 63) >> 4;
  int swz = (lr & 7) << 4;

  const unsigned short* Qg = qb + ((size_t)bh << 16);   // [n][hd]
  const unsigned short* Kg = kb + ((size_t)bh << 16);   // [n][hd]
  const unsigned short* Vg = vb + ((size_t)bh << 16);   // [hd][n]

  bf16x8 qf[2];
#pragma unroll
  for (int t = 0; t < 2; ++t)
    qf[t] = *(const bf16x8*)(Qg + (size_t)(q0 + w * 16 + lr) * HD_ + lg * 8 + t * 32);

  int cc = tid & 7;
  int r0s = tid >> 3;

#pragma unroll
  for (int p = 0; p < 2; ++p) {
    int r = r0s + 32 * p;
    int4 kv = *(const int4*)(Kg + (size_t)r * HD_ + cc * 8);
    int4 vv = *(const int4*)(Vg + (size_t)r * N_ + cc * 8);
    *(int4*)lds_at(Ks[0], r * 128 + ((cc * 16) ^ ((r & 7) << 4))) = kv;
    *(int4*)lds_at(Vs[0], r * 128 + ((cc * 16) ^ ((r & 7) << 4))) = vv;
  }
  __syncthreads();

  f32x4 oacc[4] = {};
  float mrun = -1.0e30f, lrun = 0.f;

  for (int st = 0; st < 16; ++st) {
    int cur = st & 1, nxt = cur ^ 1;
    int4 kpre[2], vpre[2];
    if (st < 15) {
      int s0n = (st + 1) * 64;
#pragma unroll
      for (int p = 0; p < 2; ++p) {
        int r = r0s + 32 * p;
        kpre[p] = *(const int4*)(Kg + (size_t)(s0n + r) * HD_ + cc * 8);
        vpre[p] = *(const int4*)(Vg + (size_t)r * N_ + s0n + cc * 8);
      }
    }

    f32x4 sacc[4] = {};
#pragma unroll
    for (int t = 0; t < 2; ++t)
#pragma unroll
      for (int f = 0; f < 4; ++f) {
        bf16x8 ka = *(const bf16x8*)lds_at(Ks[cur],
                        (16 * f + lr) * 128 + ((lg * 16 + t * 64) ^ swz));
        sacc[f] = __builtin_amdgcn_mfma_f32_16x16x32_bf16(ka, qf[t], sacc[f], 0, 0, 0);
      }

    float mt = sacc[0][0];
#pragma unroll
    for (int f = 0; f < 4; ++f)
#pragma unroll
      for (int i = 0; i < 4; ++i) mt = fmaxf(mt, sacc[f][i]);
    mt = fmaxf(mt, __shfl_xor(mt, 16));
    mt = fmaxf(mt, __shfl_xor(mt, 32));
    float mnew = fmaxf(mrun, mt);
    float corr = EXP2(mrun - mnew);
    mrun = mnew;
    float psum = 0.f;
    int qrow = w * 16 + lr;
#pragma unroll
    for (int f = 0; f < 4; ++f) {
      float p0 = EXP2(sacc[f][0] - mnew);
      float p1 = EXP2(sacc[f][1] - mnew);
      float p2 = EXP2(sacc[f][2] - mnew);
      float p3 = EXP2(sacc[f][3] - mnew);
      psum += (p0 + p1) + (p2 + p3);
      uint2 pw;
      pw.x = (unsigned int)f2bf(p0) | ((unsigned int)f2bf(p1) << 16);
      pw.y = (unsigned int)f2bf(p2) | ((unsigned int)f2bf(p3) << 16);
      *(uint2*)lds_at(Ps, qrow * 128 + ((32 * f + 8 * lg) ^ swz)) = pw;
    }
    psum += __shfl_xor(psum, 16);
    psum += __shfl_xor(psum, 32);
    lrun = lrun * corr + psum;
#pragma unroll
    for (int f = 0; f < 4; ++f)
#pragma unroll
      for (int i = 0; i < 4; ++i) oacc[f][i] *= corr;

    bf16x8 pfr[2];
#pragma unroll
    for (int t = 0; t < 2; ++t)
      pfr[t] = *(const bf16x8*)lds_at(Ps, qrow * 128 + ((lg * 16 + t * 64) ^ swz));
#pragma unroll
    for (int t = 0; t < 2; ++t)
#pragma unroll
      for (int f = 0; f < 4; ++f) {
        bf16x8 va = *(const bf16x8*)lds_at(Vs[cur],
                        (16 * f + lr) * 128 + ((lg * 16 + t * 64) ^ swz));
        oacc[f] = __builtin_amdgcn_mfma_f32_16x16x32_bf16(va, pfr[t], oacc[f], 0, 0, 0);
      }

    if (st < 15) {
#pragma unroll
      for (int p = 0; p < 2; ++p) {
        int r = r0s + 32 * p;
        *(int4*)lds_at(Ks[nxt], r * 128 + ((cc * 16) ^ ((r & 7) << 4))) = kpre[p];
        *(int4*)lds_at(Vs[nxt], r * 128 + ((cc * 16) ^ ((r & 7) << 4))) = vpre[p];
      }
      __syncthreads();
    }
  }

  float inv = 1.0f / lrun;
  int q = q0 + w * 16 + lr;
  int b = bh >> 3, head = bh & 7;
  float* dst = hb + ((size_t)b * N_ + q) * C_ + head * HD_;
#pragma unroll
  for (int f = 0; f < 4; ++f) {
    float4 o4 = {oacc[f][0] * inv, oacc[f][1] * inv, oacc[f][2] * inv, oacc[f][3] * inv};
    *(float4*)(dst + 16 * f + 4 * lg) = o4;
  }
}

// ---------------------------------------------------------------------------
// Kernel 4: proj GEMM + bias + residual (fp32, unchanged).
// ---------------------------------------------------------------------------
__global__ __launch_bounds__(256, 2) void proj_gemm(const float* __restrict__ hb,
                                                    const float* __restrict__ w,
                                                    const float* __restrict__ bias,
                                                    const float* __restrict__ x,
                                                    float* __restrict__ out) {
  __shared__ float As[16][64];
  __shared__ float Ws[16][132];
  int b = blockIdx.z, n0 = blockIdx.x * 64, o0 = blockIdx.y * 128;
  int tid = threadIdx.x;
  int tm = tid & 15, tn = tid >> 4;
  float acc[4][8] = {};
  int mmA = tid >> 2;
  int k4  = (tid & 3) * 4;
  int ooW = tid >> 1;
  int k8  = (tid & 1) * 8;
  const float* Abase = hb + (size_t)b * N_ * C_;
  const float* Wbase = w + (size_t)(o0 + ooW) * C_;

  for (int c0 = 0; c0 < C_; c0 += 16) {
    float4 a0 = *(const float4*)(Abase + (size_t)(n0 + mmA) * C_ + c0 + k4);
    float4 w0 = *(const float4*)(Wbase + c0 + k8);
    float4 w1 = *(const float4*)(Wbase + c0 + k8 + 4);
    __syncthreads();
    As[k4 + 0][mmA] = a0.x; As[k4 + 1][mmA] = a0.y;
    As[k4 + 2][mmA] = a0.z; As[k4 + 3][mmA] = a0.w;
    Ws[k8 + 0][ooW] = w0.x; Ws[k8 + 1][ooW] = w0.y;
    Ws[k8 + 2][ooW] = w0.z; Ws[k8 + 3][ooW] = w0.w;
    Ws[k8 + 4][ooW] = w1.x; Ws[k8 + 5][ooW] = w1.y;
    Ws[k8 + 6][ooW] = w1.z; Ws[k8 + 7][ooW] = w1.w;
    __syncthreads();
#pragma unroll
    for (int kk = 0; kk < 16; ++kk) {
      float4 xa = *(const float4*)&As[kk][tm * 4];
      float4 y0 = *(const float4*)&Ws[kk][tn * 4];
      float4 y1 = *(const float4*)&Ws[kk][tn * 4 + 64];
      float av[4] = {xa.x, xa.y, xa.z, xa.w};
      float wv[8] = {y0.x, y0.y, y0.z, y0.w, y1.x, y1.y, y1.z, y1.w};
#pragma unroll
      for (int i = 0; i < 4; ++i)
#pragma unroll
        for (int j = 0; j < 8; ++j) acc[i][j] = fmaf(av[i], wv[j], acc[i][j]);
    }
  }

  int n4 = n0 + tm * 4;
#pragma unroll
  for (int jg = 0; jg < 2; ++jg) {
#pragma unroll
    for (int jj = 0; jj < 4; ++jj) {
      int o = o0 + tn * 4 + jg * 64 + jj;
      float bo = bias[o];
      const float* xr = x + ((size_t)b * C_ + o) * N_ + n4;
      float4 xv = *(const float4*)xr;
      float4 r;
      r.x = acc[0][jg * 4 + jj] + bo + xv.x;
      r.y = acc[1][jg * 4 + jj] + bo + xv.y;
      r.z = acc[2][jg * 4 + jj] + bo + xv.z;
      r.w = acc[3][jg * 4 + jj] + bo + xv.w;
      *(float4*)(out + ((size_t)b * C_ + o) * N_ + n4) = r;
    }
  }
}

// ---------------------------------------------------------------------------
extern "C" void kernel_launch(void* const* d_in, const int* in_sizes, int n_in,
                              void* d_out, int out_size, void* d_ws, size_t ws_size,
                              hipStream_t stream) {
  const float* x      = (const float*)d_in[0];
  const float* norm_w = (const float*)d_in[1];
  const float* norm_b = (const float*)d_in[2];
  const float* qkv_w  = (const float*)d_in[3];
  const float* proj_w = (const float*)d_in[4];
  const float* proj_b = (const float*)d_in[5];
  float* out = (float*)d_out;

  // ws layout: [0,16MB) hb fp32 (attn output)
  //            [16,24) qb bf16  [24,32) kb bf16  [32,40) vb bf16
  //            [40,48) xn16 fp16 [b][n][c]   [48,49.5) w16 fp16
  float* hb = (float*)d_ws;
  unsigned short* qb = (unsigned short*)((char*)d_ws + (16u << 20));
  unsigned short* kb = (unsigned short*)((char*)d_ws + (24u << 20));
  unsigned short* vb = (unsigned short*)((char*)d_ws + (32u << 20));
  _Float16* xn16 = (_Float16*)((char*)d_ws + (40u << 20));
  _Float16* w16  = (_Float16*)((char*)d_ws + (48u << 20));

  wcvt_kernel<<<768, 256, 0, stream>>>(qkv_w, w16);   // 1536*512/1024 = 768
  gn_kernel<<<256, 256, 0, stream>>>(x, norm_w, norm_b, xn16);
  qkv_gemm<<<dim3(12, 64), 256, 0, stream>>>(xn16, w16, qb, kb, vb);
  attn_kernel<<<dim3(64, 16), 256, 0, stream>>>(qb, kb, vb, hb);
  proj_gemm<<<dim3(16, 4, 8), 256, 0, stream>>>(hb, proj_w, proj_b, x, out);
}

// Round 12
// 178.296 us; speedup vs baseline: 11.8935x; 1.1245x over previous
//
#include <hip/hip_runtime.h>
#include <cstdint>
#include <cstddef>

#define B_   8
#define C_   512
#define N_   1024   // H*W
#define NH_  8
#define HD_  64
#define G_   32
#define CPG_ 16     // C_/G_

typedef __attribute__((ext_vector_type(8))) __bf16 bf16x8;
typedef __attribute__((ext_vector_type(8))) _Float16 f16x8;
typedef __attribute__((ext_vector_type(4))) _Float16 f16x4;
typedef __attribute__((ext_vector_type(4))) float f32x4;

#if __has_builtin(__builtin_amdgcn_exp2f)
#define EXP2(x) __builtin_amdgcn_exp2f(x)
#else
#define EXP2(x) exp2f(x)
#endif

__device__ __forceinline__ unsigned short f2bf(float f) {  // RNE fp32->bf16
  union { float f; unsigned int u; } c; c.f = f;
  return (unsigned short)((c.u + 0x7FFFu + ((c.u >> 16) & 1u)) >> 16);
}

__device__ __forceinline__ void* lds_at(void* base, int byte_off) {
  return (void*)((char*)base + byte_off);
}

// ---------------------------------------------------------------------------
// Kernel 0: weight fp32 -> fp16 converter (grid sized exactly: n/1024 blocks)
// ---------------------------------------------------------------------------
__global__ __launch_bounds__(256) void wcvt_kernel(const float* __restrict__ w,
                                                   _Float16* __restrict__ w16) {
  int i = (blockIdx.x * 256 + threadIdx.x) * 4;
  float4 v = *(const float4*)(w + i);
  f16x4 h;
  h[0] = (_Float16)v.x; h[1] = (_Float16)v.y;
  h[2] = (_Float16)v.z; h[3] = (_Float16)v.w;
  *(f16x4*)(w16 + i) = h;
}

// ---------------------------------------------------------------------------
// Kernel 1: GroupNorm -> fp16 xn16 in TRANSPOSED layout [b][n][c].
// ---------------------------------------------------------------------------
__global__ __launch_bounds__(256) void gn_kernel(const float* __restrict__ x,
                                                 const float* __restrict__ gw,
                                                 const float* __restrict__ gb,
                                                 _Float16* __restrict__ xn16) {
  int bid = blockIdx.x;
  int b = bid >> 5, g = bid & 31;
  const float* base = x + ((size_t)b * C_ + (size_t)g * CPG_) * N_;
  float4 vals[16];
  float4 s4 = {0.f, 0.f, 0.f, 0.f}, q4 = {0.f, 0.f, 0.f, 0.f};
#pragma unroll
  for (int u = 0; u < 16; ++u) {
    float4 v = *(const float4*)(base + (size_t)u * N_ + threadIdx.x * 4);
    vals[u] = v;
    s4.x += v.x; s4.y += v.y; s4.z += v.z; s4.w += v.w;
    q4.x += v.x * v.x; q4.y += v.y * v.y; q4.z += v.z * v.z; q4.w += v.w * v.w;
  }
  float s = (s4.x + s4.y) + (s4.z + s4.w);
  float q = (q4.x + q4.y) + (q4.z + q4.w);
#pragma unroll
  for (int off = 32; off; off >>= 1) {
    s += __shfl_xor(s, off);
    q += __shfl_xor(q, off);
  }
  __shared__ float sm[4], sq[4];
  __shared__ float smean, srstd;
  int wid = threadIdx.x >> 6;
  if ((threadIdx.x & 63) == 0) { sm[wid] = s; sq[wid] = q; }
  __syncthreads();
  if (threadIdx.x == 0) {
    float S = (sm[0] + sm[1]) + (sm[2] + sm[3]);
    float Q = (sq[0] + sq[1]) + (sq[2] + sq[3]);
    float mean = S * (1.0f / 16384.0f);
    float var  = Q * (1.0f / 16384.0f) - mean * mean;
    smean = mean;
    srstd = rsqrtf(var + 1e-5f);
  }
  __syncthreads();
  float mean = smean, rstd = srstd;
  float aa[16], bb2[16];
#pragma unroll
  for (int u = 0; u < 16; ++u) {
    int c = g * CPG_ + u;
    aa[u]  = rstd * gw[c];
    bb2[u] = gb[c] - mean * aa[u];
  }
#pragma unroll
  for (int i = 0; i < 4; ++i) {
    f16x8 lo, hi;
#pragma unroll
    for (int u = 0; u < 8; ++u)
      lo[u] = (_Float16)(((const float*)&vals[u])[i] * aa[u] + bb2[u]);
#pragma unroll
    for (int u = 0; u < 8; ++u)
      hi[u] = (_Float16)(((const float*)&vals[u + 8])[i] * aa[u + 8] + bb2[u + 8]);
    size_t dst = ((size_t)b * N_ + (size_t)(threadIdx.x * 4 + i)) * C_ + g * CPG_;
    *(f16x8*)(xn16 + dst)     = lo;
    *(f16x8*)(xn16 + dst + 8) = hi;
  }
}

// ---------------------------------------------------------------------------
// Kernel 2: QKV GEMM, fp16 MFMA (validated R11). A = W16 rows (o),
// B = xn16 rows (n). Epilogue -> bf16 q/k/v for attn.
// ---------------------------------------------------------------------------
__global__ __launch_bounds__(256, 2) void qkv_gemm(const _Float16* __restrict__ xn16,
                                                   const _Float16* __restrict__ w16,
                                                   unsigned short* __restrict__ qb,
                                                   unsigned short* __restrict__ kbf,
                                                   unsigned short* __restrict__ vbf) {
  __shared__ _Float16 Wl[2][8192];   // [o:128][c:64] swizzled
  __shared__ _Float16 Xl[2][8192];   // [n:128][c:64] swizzled

  int ot = blockIdx.x;               // 0..11
  int nt = blockIdx.y;               // 0..63
  int tid = threadIdx.x;
  int lr = tid & 15;
  int lg = (tid & 63) >> 4;
  int w  = tid >> 6;
  int wo = w >> 1, wn = w & 1;
  int o0 = ot * 128;
  int swz = (lr & 7) << 4;

  int cc = tid & 7;
  int r0 = tid >> 3;
  const _Float16* Wg = w16 + (size_t)o0 * C_;
  const _Float16* Xg = xn16 + (size_t)(nt * 128) * C_;

#pragma unroll
  for (int p = 0; p < 4; ++p) {
    int r = r0 + 32 * p;
    int4 wv = *(const int4*)(Wg + (size_t)r * C_ + cc * 8);
    int4 xv = *(const int4*)(Xg + (size_t)r * C_ + cc * 8);
    *(int4*)lds_at(Wl[0], r * 128 + ((cc * 16) ^ ((r & 7) << 4))) = wv;
    *(int4*)lds_at(Xl[0], r * 128 + ((cc * 16) ^ ((r & 7) << 4))) = xv;
  }
  __syncthreads();

  f32x4 acc[4][4] = {};

  for (int ks = 0; ks < 8; ++ks) {
    int cur = ks & 1, nxt = cur ^ 1;
    int4 wpre[4], xpre[4];
    if (ks < 7) {
      int k0n = (ks + 1) * 64;
#pragma unroll
      for (int p = 0; p < 4; ++p) {
        int r = r0 + 32 * p;
        wpre[p] = *(const int4*)(Wg + (size_t)r * C_ + k0n + cc * 8);
        xpre[p] = *(const int4*)(Xg + (size_t)r * C_ + k0n + cc * 8);
      }
    }
#pragma unroll
    for (int t = 0; t < 2; ++t) {
      f16x8 af[4], bf[4];
#pragma unroll
      for (int f = 0; f < 4; ++f)
        af[f] = *(const f16x8*)lds_at(Wl[cur],
                    (wo * 64 + f * 16 + lr) * 128 + ((t * 64 + lg * 16) ^ swz));
#pragma unroll
      for (int f = 0; f < 4; ++f)
        bf[f] = *(const f16x8*)lds_at(Xl[cur],
                    (wn * 64 + f * 16 + lr) * 128 + ((t * 64 + lg * 16) ^ swz));
#pragma unroll
      for (int fo = 0; fo < 4; ++fo)
#pragma unroll
        for (int fn = 0; fn < 4; ++fn)
          acc[fo][fn] = __builtin_amdgcn_mfma_f32_16x16x32_f16(af[fo], bf[fn],
                                                               acc[fo][fn], 0, 0, 0);
    }
    if (ks < 7) {
#pragma unroll
      for (int p = 0; p < 4; ++p) {
        int r = r0 + 32 * p;
        *(int4*)lds_at(Wl[nxt], r * 128 + ((cc * 16) ^ ((r & 7) << 4))) = wpre[p];
        *(int4*)lds_at(Xl[nxt], r * 128 + ((cc * 16) ^ ((r & 7) << 4))) = xpre[p];
      }
      __syncthreads();
    }
  }

  const float qkscale = 0.4246609f;  // 64^-0.25 * sqrt(log2(e))
#pragma unroll
  for (int fo = 0; fo < 4; ++fo) {
#pragma unroll
    for (int fn = 0; fn < 4; ++fn) {
      int ob4 = o0 + wo * 64 + fo * 16 + lg * 4;
      int ngl = nt * 128 + wn * 64 + fn * 16 + lr;
      int b = ngl >> 10, n = ngl & 1023;
      int head = ob4 / 192;
      int r = ob4 - head * 192;
      int kind = r >> 6;
      int hd0 = r & 63;
      size_t bhbase = (size_t)(b * NH_ + head) * ((size_t)HD_ * N_);
      f32x4 a = acc[fo][fn];
      if (kind < 2) {
        unsigned short* buf = kind ? kbf : qb;
        ushort4 u;
        u.x = f2bf(a[0] * qkscale); u.y = f2bf(a[1] * qkscale);
        u.z = f2bf(a[2] * qkscale); u.w = f2bf(a[3] * qkscale);
        *(ushort4*)(buf + bhbase + (size_t)n * HD_ + hd0) = u;
      } else {
#pragma unroll
        for (int i = 0; i < 4; ++i)
          vbf[bhbase + (size_t)(hd0 + i) * N_ + n] = f2bf(a[i]);
      }
    }
  }
}

// ---------------------------------------------------------------------------
// Kernel 3: flash attention, bf16 MFMA (validated R7/R11).
// ONLY change this round: epilogue writes hb in fp16 (proj B-operand).
// ---------------------------------------------------------------------------
__global__ __launch_bounds__(256, 4) void attn_kernel(const unsigned short* __restrict__ qb,
                                                      const unsigned short* __restrict__ kb,
                                                      const unsigned short* __restrict__ vb,
                                                      _Float16* __restrict__ hb16) {
  __shared__ unsigned short Ks[2][4096];
  __shared__ unsigned short Vs[2][4096];
  __shared__ unsigned short Ps[4096];

  int bh = blockIdx.x;
  int q0 = blockIdx.y * 64;
  int tid = threadIdx.x;
  int w  = tid >> 6;
  int lr = tid & 15;
  int lg = (tid & 63) >> 4;
  int swz = (lr & 7) << 4;

  const unsigned short* Qg = qb + ((size_t)bh << 16);
  const unsigned short* Kg = kb + ((size_t)bh << 16);
  const unsigned short* Vg = vb + ((size_t)bh << 16);

  bf16x8 qf[2];
#pragma unroll
  for (int t = 0; t < 2; ++t)
    qf[t] = *(const bf16x8*)(Qg + (size_t)(q0 + w * 16 + lr) * HD_ + lg * 8 + t * 32);

  int cc = tid & 7;
  int r0s = tid >> 3;

#pragma unroll
  for (int p = 0; p < 2; ++p) {
    int r = r0s + 32 * p;
    int4 kv = *(const int4*)(Kg + (size_t)r * HD_ + cc * 8);
    int4 vv = *(const int4*)(Vg + (size_t)r * N_ + cc * 8);
    *(int4*)lds_at(Ks[0], r * 128 + ((cc * 16) ^ ((r & 7) << 4))) = kv;
    *(int4*)lds_at(Vs[0], r * 128 + ((cc * 16) ^ ((r & 7) << 4))) = vv;
  }
  __syncthreads();

  f32x4 oacc[4] = {};
  float mrun = -1.0e30f, lrun = 0.f;

  for (int st = 0; st < 16; ++st) {
    int cur = st & 1, nxt = cur ^ 1;
    int4 kpre[2], vpre[2];
    if (st < 15) {
      int s0n = (st + 1) * 64;
#pragma unroll
      for (int p = 0; p < 2; ++p) {
        int r = r0s + 32 * p;
        kpre[p] = *(const int4*)(Kg + (size_t)(s0n + r) * HD_ + cc * 8);
        vpre[p] = *(const int4*)(Vg + (size_t)r * N_ + s0n + cc * 8);
      }
    }

    f32x4 sacc[4] = {};
#pragma unroll
    for (int t = 0; t < 2; ++t)
#pragma unroll
      for (int f = 0; f < 4; ++f) {
        bf16x8 ka = *(const bf16x8*)lds_at(Ks[cur],
                        (16 * f + lr) * 128 + ((lg * 16 + t * 64) ^ swz));
        sacc[f] = __builtin_amdgcn_mfma_f32_16x16x32_bf16(ka, qf[t], sacc[f], 0, 0, 0);
      }

    float mt = sacc[0][0];
#pragma unroll
    for (int f = 0; f < 4; ++f)
#pragma unroll
      for (int i = 0; i < 4; ++i) mt = fmaxf(mt, sacc[f][i]);
    mt = fmaxf(mt, __shfl_xor(mt, 16));
    mt = fmaxf(mt, __shfl_xor(mt, 32));
    float mnew = fmaxf(mrun, mt);
    float corr = EXP2(mrun - mnew);
    mrun = mnew;
    float psum = 0.f;
    int qrow = w * 16 + lr;
#pragma unroll
    for (int f = 0; f < 4; ++f) {
      float p0 = EXP2(sacc[f][0] - mnew);
      float p1 = EXP2(sacc[f][1] - mnew);
      float p2 = EXP2(sacc[f][2] - mnew);
      float p3 = EXP2(sacc[f][3] - mnew);
      psum += (p0 + p1) + (p2 + p3);
      uint2 pw;
      pw.x = (unsigned int)f2bf(p0) | ((unsigned int)f2bf(p1) << 16);
      pw.y = (unsigned int)f2bf(p2) | ((unsigned int)f2bf(p3) << 16);
      *(uint2*)lds_at(Ps, qrow * 128 + ((32 * f + 8 * lg) ^ swz)) = pw;
    }
    psum += __shfl_xor(psum, 16);
    psum += __shfl_xor(psum, 32);
    lrun = lrun * corr + psum;
#pragma unroll
    for (int f = 0; f < 4; ++f)
#pragma unroll
      for (int i = 0; i < 4; ++i) oacc[f][i] *= corr;

    bf16x8 pfr[2];
#pragma unroll
    for (int t = 0; t < 2; ++t)
      pfr[t] = *(const bf16x8*)lds_at(Ps, qrow * 128 + ((lg * 16 + t * 64) ^ swz));
#pragma unroll
    for (int t = 0; t < 2; ++t)
#pragma unroll
      for (int f = 0; f < 4; ++f) {
        bf16x8 va = *(const bf16x8*)lds_at(Vs[cur],
                        (16 * f + lr) * 128 + ((lg * 16 + t * 64) ^ swz));
        oacc[f] = __builtin_amdgcn_mfma_f32_16x16x32_bf16(va, pfr[t], oacc[f], 0, 0, 0);
      }

    if (st < 15) {
#pragma unroll
      for (int p = 0; p < 2; ++p) {
        int r = r0s + 32 * p;
        *(int4*)lds_at(Ks[nxt], r * 128 + ((cc * 16) ^ ((r & 7) << 4))) = kpre[p];
        *(int4*)lds_at(Vs[nxt], r * 128 + ((cc * 16) ^ ((r & 7) << 4))) = vpre[p];
      }
      __syncthreads();
    }
  }

  // epilogue: O = O^T/l -> hb16[b][n=q][c] fp16
  float inv = 1.0f / lrun;
  int q = q0 + w * 16 + lr;
  int b = bh >> 3, head = bh & 7;
  _Float16* dst = hb16 + ((size_t)b * N_ + q) * C_ + head * HD_;
#pragma unroll
  for (int f = 0; f < 4; ++f) {
    f16x4 o4;
    o4[0] = (_Float16)(oacc[f][0] * inv); o4[1] = (_Float16)(oacc[f][1] * inv);
    o4[2] = (_Float16)(oacc[f][2] * inv); o4[3] = (_Float16)(oacc[f][3] * inv);
    *(f16x4*)(dst + 16 * f + 4 * lg) = o4;
  }
}

// ---------------------------------------------------------------------------
// Kernel 4: proj GEMM, fp16 MFMA — clone of qkv_gemm structure (validated).
//   A = proj_w16 rows (M = o, 512), B = hb16 rows (N = b*n, 8192), K = c.
//   Epilogue: out[b][o][n] = acc + bias[o] + x[b][o][n]  (fp32 store).
// ---------------------------------------------------------------------------
__global__ __launch_bounds__(256, 2) void proj_gemm(const _Float16* __restrict__ hb16,
                                                    const _Float16* __restrict__ pw16,
                                                    const float* __restrict__ bias,
                                                    const float* __restrict__ x,
                                                    float* __restrict__ out) {
  __shared__ _Float16 Wl[2][8192];   // [o:128][c:64] swizzled
  __shared__ _Float16 Xl[2][8192];   // [n:128][c:64] swizzled

  int ot = blockIdx.x;               // 0..3
  int nt = blockIdx.y;               // 0..63
  int tid = threadIdx.x;
  int lr = tid & 15;
  int lg = (tid & 63) >> 4;
  int w  = tid >> 6;
  int wo = w >> 1, wn = w & 1;
  int o0 = ot * 128;
  int swz = (lr & 7) << 4;

  int cc = tid & 7;
  int r0 = tid >> 3;
  const _Float16* Wg = pw16 + (size_t)o0 * C_;
  const _Float16* Xg = hb16 + (size_t)(nt * 128) * C_;

#pragma unroll
  for (int p = 0; p < 4; ++p) {
    int r = r0 + 32 * p;
    int4 wv = *(const int4*)(Wg + (size_t)r * C_ + cc * 8);
    int4 xv = *(const int4*)(Xg + (size_t)r * C_ + cc * 8);
    *(int4*)lds_at(Wl[0], r * 128 + ((cc * 16) ^ ((r & 7) << 4))) = wv;
    *(int4*)lds_at(Xl[0], r * 128 + ((cc * 16) ^ ((r & 7) << 4))) = xv;
  }
  __syncthreads();

  f32x4 acc[4][4] = {};

  for (int ks = 0; ks < 8; ++ks) {
    int cur = ks & 1, nxt = cur ^ 1;
    int4 wpre[4], xpre[4];
    if (ks < 7) {
      int k0n = (ks + 1) * 64;
#pragma unroll
      for (int p = 0; p < 4; ++p) {
        int r = r0 + 32 * p;
        wpre[p] = *(const int4*)(Wg + (size_t)r * C_ + k0n + cc * 8);
        xpre[p] = *(const int4*)(Xg + (size_t)r * C_ + k0n + cc * 8);
      }
    }
#pragma unroll
    for (int t = 0; t < 2; ++t) {
      f16x8 af[4], bf[4];
#pragma unroll
      for (int f = 0; f < 4; ++f)
        af[f] = *(const f16x8*)lds_at(Wl[cur],
                    (wo * 64 + f * 16 + lr) * 128 + ((t * 64 + lg * 16) ^ swz));
#pragma unroll
      for (int f = 0; f < 4; ++f)
        bf[f] = *(const f16x8*)lds_at(Xl[cur],
                    (wn * 64 + f * 16 + lr) * 128 + ((t * 64 + lg * 16) ^ swz));
#pragma unroll
      for (int fo = 0; fo < 4; ++fo)
#pragma unroll
        for (int fn = 0; fn < 4; ++fn)
          acc[fo][fn] = __builtin_amdgcn_mfma_f32_16x16x32_f16(af[fo], bf[fn],
                                                               acc[fo][fn], 0, 0, 0);
    }
    if (ks < 7) {
#pragma unroll
      for (int p = 0; p < 4; ++p) {
        int r = r0 + 32 * p;
        *(int4*)lds_at(Wl[nxt], r * 128 + ((cc * 16) ^ ((r & 7) << 4))) = wpre[p];
        *(int4*)lds_at(Xl[nxt], r * 128 + ((cc * 16) ^ ((r & 7) << 4))) = xpre[p];
      }
      __syncthreads();
    }
  }

  // epilogue: D col = n (lr), rows o = lg*4+i; + bias + residual -> fp32 out
#pragma unroll
  for (int fo = 0; fo < 4; ++fo) {
#pragma unroll
    for (int fn = 0; fn < 4; ++fn) {
      int o4 = o0 + wo * 64 + fo * 16 + lg * 4;
      int ngl = nt * 128 + wn * 64 + fn * 16 + lr;
      int b = ngl >> 10, n = ngl & 1023;
      f32x4 a = acc[fo][fn];
#pragma unroll
      for (int i = 0; i < 4; ++i) {
        int o = o4 + i;
        size_t idx = ((size_t)b * C_ + o) * N_ + n;
        out[idx] = a[i] + bias[o] + x[idx];
      }
    }
  }
}

// ---------------------------------------------------------------------------
extern "C" void kernel_launch(void* const* d_in, const int* in_sizes, int n_in,
                              void* d_out, int out_size, void* d_ws, size_t ws_size,
                              hipStream_t stream) {
  const float* x      = (const float*)d_in[0];
  const float* norm_w = (const float*)d_in[1];
  const float* norm_b = (const float*)d_in[2];
  const float* qkv_w  = (const float*)d_in[3];
  const float* proj_w = (const float*)d_in[4];
  const float* proj_b = (const float*)d_in[5];
  float* out = (float*)d_out;

  // ws layout: [0,8MB) hb16 fp16 [b][n][c]
  //            [16,24) qb bf16  [24,32) kb bf16  [32,40) vb bf16
  //            [40,48) xn16 fp16 [b][n][c]
  //            [48,49.5) w16 (qkv) fp16   [50,50.5) pw16 (proj) fp16
  _Float16* hb16 = (_Float16*)d_ws;
  unsigned short* qb = (unsigned short*)((char*)d_ws + (16u << 20));
  unsigned short* kb = (unsigned short*)((char*)d_ws + (24u << 20));
  unsigned short* vb = (unsigned short*)((char*)d_ws + (32u << 20));
  _Float16* xn16 = (_Float16*)((char*)d_ws + (40u << 20));
  _Float16* w16  = (_Float16*)((char*)d_ws + (48u << 20));
  _Float16* pw16 = (_Float16*)((char*)d_ws + (50u << 20));

  wcvt_kernel<<<768, 256, 0, stream>>>(qkv_w, w16);    // 1536*512 / 1024
  wcvt_kernel<<<256, 256, 0, stream>>>(proj_w, pw16);  // 512*512 / 1024
  gn_kernel<<<256, 256, 0, stream>>>(x, norm_w, norm_b, xn16);
  qkv_gemm<<<dim3(12, 64), 256, 0, stream>>>(xn16, w16, qb, kb, vb);
  attn_kernel<<<dim3(64, 16), 256, 0, stream>>>(qb, kb, vb, hb16);
  proj_gemm<<<dim3(4, 64), 256, 0, stream>>>(hb16, pw16, proj_b, x, out);
}